// Round 3
// baseline (205883.398 us; speedup 1.0000x reference)
//
#include <hip/hip_runtime.h>
#include <cstdint>
#include <cmath>

// ---------------- constants ----------------
#define BB 32
#define TT 512
#define EE 768
#define HH 3132
#define HP 3136   // H padded to mult of 64
#define OO 19

#define NBLK 512
#define NTHR 256
#define LDA 232   // LDS A row pitch (224 used + pad), rows 16B-aligned

// phase-A task ranges
#define T1_N 686            // 49 nt * 14 ks   (Whh1 @ h1, split, 7 ksteps)
#define T1X_N 147           // 49 nt * 3 ks    (Wih1 @ xn, split, 8 ksteps)
#define T2_N 168            // 12 nt * 14 ks   (Wih2 @ h1, hi, 7 ksteps)
#define T3_N 36             // 12 nt * 3 ks    (Whh2 @ h2, splitA, 8 ksteps)
#define PA_TASKS (T1_N + T1X_N + T2_N + T3_N)   // 1037
// phase-B task ranges
#define U1_N 512            // 32 b * 16 chunks of 196
#define U2_N 32
#define PB_TASKS (U1_N + U2_N)                   // 544
#define SLOT1 17
#define SLOT2 17

typedef __attribute__((ext_vector_type(8))) short s8v;
typedef __attribute__((ext_vector_type(4))) float f4v;

__device__ __forceinline__ unsigned short f2bf(float f) {
    uint32_t u = __float_as_uint(f);
    uint32_t r = u + 0x7FFFu + ((u >> 16) & 1u);
    return (unsigned short)(r >> 16);
}
__device__ __forceinline__ float bf2f(unsigned short h) {
    return __uint_as_float(((uint32_t)h) << 16);
}

#define MFMA(a, b, c) __builtin_amdgcn_mfma_f32_16x16x32_bf16((a), (b), (c), 0, 0, 0)

// ---------------- grid barrier (cumulative counter) ----------------
__device__ __forceinline__ void gbar(unsigned int* cnt, unsigned int k) {
    __syncthreads();
    if (threadIdx.x == 0) {
        __threadfence();
        __hip_atomic_fetch_add(cnt, 1u, __ATOMIC_ACQ_REL, __HIP_MEMORY_SCOPE_AGENT);
        unsigned int target = k * NBLK;
        long guard = 0;
        while (__hip_atomic_load(cnt, __ATOMIC_ACQUIRE, __HIP_MEMORY_SCOPE_AGENT) < target) {
            __builtin_amdgcn_s_sleep(2);
            if (++guard > (1L << 22)) break;   // watchdog: never hang
        }
    }
    __syncthreads();
}

// ---------------- persistent-kernel params ----------------
struct PP {
    const unsigned short *xnhi, *xnlo;
    const unsigned short *wih1hi, *wih1lo, *whh1hi, *whh1lo, *wih2, *whh2;
    const float *b1c, *b2c, *g1, *be1;
    float *v, *stats;
    unsigned short *h2hi, *h2lo;
    float *part1, *part2;
    unsigned short *h1s, *h2s;
    unsigned int *cnt;
};

// build normalized A (32 x 224 slice at k0) into LDS from (v, stats); optional lo; optional h1s snapshot
__device__ __forceinline__ void buildA(const PP& p, int k0, bool withLo, bool snap, int t,
                                       unsigned short (*Ahi)[LDA], unsigned short (*Alo)[LDA],
                                       float* mB, float* invB) {
    int tid = threadIdx.x;
    __syncthreads();
    if (tid < 32) {
        float s = 0.f, s2 = 0.f;
        #pragma unroll
        for (int c = 0; c < 16; ++c) {
            s  += p.stats[(tid * 16 + c) * 2];
            s2 += p.stats[(tid * 16 + c) * 2 + 1];
        }
        float m = s / (float)HH;
        float var = s2 / (float)HH - m * m;
        mB[tid] = m;
        invB[tid] = rsqrtf(var + 1e-5f);
    }
    __syncthreads();
    #pragma unroll
    for (int i = 0; i < 28; ++i) {
        int e = tid + i * 256;           // 28*256 = 7168 = 32*224
        int b = e / 224, kk = e - b * 224, k = k0 + kk;
        float a = 0.f;
        if (k < HH) a = (p.v[b * HP + k] - mB[b]) * invB[b] * p.g1[k] + p.be1[k];
        unsigned short hb = f2bf(a);
        Ahi[b][kk] = hb;
        if (withLo) Alo[b][kk] = f2bf(a - bf2f(hb));
        if (snap) p.h1s[((size_t)(t - 1) * BB + b) * HP + k] = hb;
    }
    __syncthreads();
}

__global__ __launch_bounds__(NTHR, 2) void persist_k(PP p) {
    __shared__ unsigned short Ahi[32][LDA];
    __shared__ unsigned short Alo[32][LDA];
    __shared__ float mB[32], invB[32];
    __shared__ float redA[4], redB[4];
    const int blk = blockIdx.x, tid = threadIdx.x;
    const int wid = tid >> 6, lane = tid & 63;
    const int r = lane & 15, kg = lane >> 4;
    unsigned int bar = 0;

    for (int t = 0; t <= TT; ++t) {
        // ============ PHASE A: GEMMs ============
        for (int task = blk; task < PA_TASKS; task += NBLK) {
            if (task < T1_N) {
                // ---- T1: part1[ks] = Whh1 @ h1[t-1]  (split precision) ----
                int nt = task / 14, ks = task % 14;
                int n0 = nt * 64, k0 = ks * 224;
                bool mf = (t <= TT - 1);
                bool snap = (t >= 1) && (nt == 0);
                bool build = (t >= 1) && (mf || snap);
                if (build) buildA(p, k0, true, snap, t, Ahi, Alo, mB, invB);
                if (mf) {
                    f4v acc0 = {0.f, 0.f, 0.f, 0.f}, acc1 = {0.f, 0.f, 0.f, 0.f};
                    if (build) {
                        const unsigned short* Whr = p.whh1hi + (size_t)(n0 + wid * 16 + r) * HP + k0 + kg * 8;
                        const unsigned short* Wlr = p.whh1lo + (size_t)(n0 + wid * 16 + r) * HP + k0 + kg * 8;
                        #pragma unroll
                        for (int s = 0; s < 7; ++s) {
                            s8v bh  = *(const s8v*)(Whr + s * 32);
                            s8v bl  = *(const s8v*)(Wlr + s * 32);
                            s8v a0h = *(const s8v*)(&Ahi[r][kg * 8 + s * 32]);
                            s8v a1h = *(const s8v*)(&Ahi[r + 16][kg * 8 + s * 32]);
                            s8v a0l = *(const s8v*)(&Alo[r][kg * 8 + s * 32]);
                            s8v a1l = *(const s8v*)(&Alo[r + 16][kg * 8 + s * 32]);
                            acc0 = MFMA(a0h, bh, acc0); acc1 = MFMA(a1h, bh, acc1);
                            acc0 = MFMA(a0l, bh, acc0); acc1 = MFMA(a1l, bh, acc1);
                            acc0 = MFMA(a0h, bl, acc0); acc1 = MFMA(a1h, bl, acc1);
                        }
                    }
                    int ncol = n0 + wid * 16 + r;
                    float* pp = p.part1 + (size_t)ks * BB * HP + ncol;
                    #pragma unroll
                    for (int q = 0; q < 4; ++q) {
                        pp[(size_t)(kg * 4 + q) * HP]      = acc0[q];
                        pp[(size_t)(kg * 4 + q + 16) * HP] = acc1[q];
                    }
                }
            } else if (task < T1_N + T1X_N) {
                // ---- T1x: part1[14+ks] = Wih1 @ xn[t]  (split precision) ----
                if (t <= TT - 1) {
                    int id2 = task - T1_N;
                    int nt = id2 / 3, ks = id2 % 3;
                    int n0 = nt * 64, k0 = ks * 256;
                    const unsigned short* A0h = p.xnhi + ((size_t)t * BB + r) * EE + k0 + kg * 8;
                    const unsigned short* A0l = p.xnlo + ((size_t)t * BB + r) * EE + k0 + kg * 8;
                    const unsigned short* Whr = p.wih1hi + (size_t)(n0 + wid * 16 + r) * EE + k0 + kg * 8;
                    const unsigned short* Wlr = p.wih1lo + (size_t)(n0 + wid * 16 + r) * EE + k0 + kg * 8;
                    f4v acc0 = {0.f, 0.f, 0.f, 0.f}, acc1 = {0.f, 0.f, 0.f, 0.f};
                    #pragma unroll
                    for (int s = 0; s < 8; ++s) {
                        s8v bh  = *(const s8v*)(Whr + s * 32);
                        s8v bl  = *(const s8v*)(Wlr + s * 32);
                        s8v a0h = *(const s8v*)(A0h + s * 32);
                        s8v a1h = *(const s8v*)(A0h + (size_t)16 * EE + s * 32);
                        s8v a0l = *(const s8v*)(A0l + s * 32);
                        s8v a1l = *(const s8v*)(A0l + (size_t)16 * EE + s * 32);
                        acc0 = MFMA(a0h, bh, acc0); acc1 = MFMA(a1h, bh, acc1);
                        acc0 = MFMA(a0l, bh, acc0); acc1 = MFMA(a1l, bh, acc1);
                        acc0 = MFMA(a0h, bl, acc0); acc1 = MFMA(a1h, bl, acc1);
                    }
                    int ncol = n0 + wid * 16 + r;
                    float* pp = p.part1 + (size_t)(14 + ks) * BB * HP + ncol;
                    #pragma unroll
                    for (int q = 0; q < 4; ++q) {
                        pp[(size_t)(kg * 4 + q) * HP]      = acc0[q];
                        pp[(size_t)(kg * 4 + q + 16) * HP] = acc1[q];
                    }
                }
            } else if (task < T1_N + T1X_N + T2_N) {
                // ---- T2: part2[ks] = Wih2 @ h1[t-1]  (hi only) ----
                int id2 = task - (T1_N + T1X_N);
                int nt = id2 / 14, ks = id2 % 14;
                int n0 = nt * 64, k0 = ks * 224;
                f4v acc0 = {0.f, 0.f, 0.f, 0.f}, acc1 = {0.f, 0.f, 0.f, 0.f};
                if (t >= 1) {
                    buildA(p, k0, false, false, t, Ahi, Alo, mB, invB);
                    const unsigned short* Whr = p.wih2 + (size_t)(n0 + wid * 16 + r) * HP + k0 + kg * 8;
                    #pragma unroll
                    for (int s = 0; s < 7; ++s) {
                        s8v bh  = *(const s8v*)(Whr + s * 32);
                        s8v a0h = *(const s8v*)(&Ahi[r][kg * 8 + s * 32]);
                        s8v a1h = *(const s8v*)(&Ahi[r + 16][kg * 8 + s * 32]);
                        acc0 = MFMA(a0h, bh, acc0); acc1 = MFMA(a1h, bh, acc1);
                    }
                }
                int ncol = n0 + wid * 16 + r;
                float* pp = p.part2 + (size_t)ks * BB * EE + ncol;
                #pragma unroll
                for (int q = 0; q < 4; ++q) {
                    pp[(size_t)(kg * 4 + q) * EE]      = acc0[q];
                    pp[(size_t)(kg * 4 + q + 16) * EE] = acc1[q];
                }
            } else {
                // ---- T3: part2[14+ks] = Whh2 @ h2state  (split A, hi W) ----
                int id2 = task - (T1_N + T1X_N + T2_N);
                int nt = id2 / 3, ks = id2 % 3;
                int n0 = nt * 64, k0 = ks * 256;
                const unsigned short* Whr = p.whh2 + (size_t)(n0 + wid * 16 + r) * EE + k0 + kg * 8;
                const unsigned short* A0h = p.h2hi + (size_t)r * EE + k0 + kg * 8;
                const unsigned short* A0l = p.h2lo + (size_t)r * EE + k0 + kg * 8;
                f4v acc0 = {0.f, 0.f, 0.f, 0.f}, acc1 = {0.f, 0.f, 0.f, 0.f};
                #pragma unroll
                for (int s = 0; s < 8; ++s) {
                    s8v bh  = *(const s8v*)(Whr + s * 32);
                    s8v a0h = *(const s8v*)(A0h + s * 32);
                    s8v a1h = *(const s8v*)(A0h + (size_t)16 * EE + s * 32);
                    s8v a0l = *(const s8v*)(A0l + s * 32);
                    s8v a1l = *(const s8v*)(A0l + (size_t)16 * EE + s * 32);
                    acc0 = MFMA(a0h, bh, acc0); acc0 = MFMA(a0l, bh, acc0);
                    acc1 = MFMA(a1h, bh, acc1); acc1 = MFMA(a1l, bh, acc1);
                }
                int ncol = n0 + wid * 16 + r;
                float* pp = p.part2 + (size_t)(14 + ks) * BB * EE + ncol;
                #pragma unroll
                for (int q = 0; q < 4; ++q) {
                    pp[(size_t)(kg * 4 + q) * EE]      = acc0[q];
                    pp[(size_t)(kg * 4 + q + 16) * EE] = acc1[q];
                }
            }
        }
        gbar(p.cnt, ++bar);

        // ============ PHASE B: pointwise ============
        for (int task = blk; task < PB_TASKS; task += NBLK) {
            if (task < U1_N) {
                if (t <= TT - 1) {
                    int b = task >> 4, c = task & 15;
                    float s = 0.f, s2 = 0.f;
                    if (tid < 196) {
                        int n = c * 196 + tid;
                        float acc = p.b1c[n];
                        #pragma unroll
                        for (int sl = 0; sl < SLOT1; ++sl)
                            acc += p.part1[((size_t)sl * BB + b) * HP + n];
                        float val = 0.f;
                        if (n < HH) { val = tanhf(acc); s = val; s2 = val * val; }
                        p.v[b * HP + n] = val;
                    }
                    for (int o = 32; o; o >>= 1) { s += __shfl_xor(s, o); s2 += __shfl_xor(s2, o); }
                    if (lane == 0) { redA[wid] = s; redB[wid] = s2; }
                    __syncthreads();
                    if (tid == 0) {
                        p.stats[(b * 16 + c) * 2]     = redA[0] + redA[1] + redA[2] + redA[3];
                        p.stats[(b * 16 + c) * 2 + 1] = redB[0] + redB[1] + redB[2] + redB[3];
                    }
                    __syncthreads();
                }
            } else {
                if (t >= 1) {
                    int b = task - U1_N;
                    #pragma unroll
                    for (int i = 0; i < 3; ++i) {
                        int n = tid + i * 256;
                        float acc = p.b2c[n];
                        #pragma unroll
                        for (int sl = 0; sl < SLOT2; ++sl)
                            acc += p.part2[((size_t)sl * BB + b) * EE + n];
                        float h = tanhf(acc);
                        unsigned short hb = f2bf(h);
                        p.h2hi[b * EE + n] = hb;
                        p.h2lo[b * EE + n] = f2bf(h - bf2f(hb));
                        p.h2s[((size_t)(t - 1) * BB + b) * EE + n] = hb;
                    }
                }
            }
        }
        gbar(p.cnt, ++bar);
    }
}

// ---------------- LN over input x, write transposed hi/lo bf16 [T][B][E] ----------------
__global__ void ln_x_k(const float* __restrict__ x, const float* __restrict__ g,
                       const float* __restrict__ be, unsigned short* __restrict__ xnhi,
                       unsigned short* __restrict__ xnlo) {
    int bt = blockIdx.x;
    int b = bt >> 9, t = bt & 511;
    const float* row = x + ((size_t)b * TT + t) * EE;
    int tid = threadIdx.x;
    float v0 = row[tid], v1 = row[tid + 256], v2 = row[tid + 512];
    float s = v0 + v1 + v2, s2 = v0 * v0 + v1 * v1 + v2 * v2;
    for (int o = 32; o; o >>= 1) { s += __shfl_xor(s, o); s2 += __shfl_xor(s2, o); }
    __shared__ float r1[4], r2[4];
    int wid = tid >> 6, lane = tid & 63;
    if (lane == 0) { r1[wid] = s; r2[wid] = s2; }
    __syncthreads();
    s = r1[0] + r1[1] + r1[2] + r1[3];
    s2 = r2[0] + r2[1] + r2[2] + r2[3];
    float m = s / (float)EE, var = s2 / (float)EE - m * m;
    float inv = rsqrtf(var + 1e-5f);
    size_t ro = ((size_t)t * BB + b) * EE;
    float vals[3] = {v0, v1, v2};
#pragma unroll
    for (int i = 0; i < 3; i++) {
        int e = tid + i * 256;
        float o = (vals[i] - m) * inv * g[e] + be[e];
        unsigned short hb = f2bf(o);
        xnhi[ro + e] = hb;
        xnlo[ro + e] = f2bf(o - bf2f(hb));
    }
}

__global__ void castpad_k(const float* __restrict__ in, int N, int K,
                          unsigned short* __restrict__ out, int Np, int Kp) {
    size_t gid = (size_t)blockIdx.x * 256 + threadIdx.x;
    if (gid >= (size_t)Np * Kp) return;
    int n = (int)(gid / Kp), k = (int)(gid % Kp);
    out[gid] = (n < N && k < K) ? f2bf(in[(size_t)n * K + k]) : (unsigned short)0;
}

__global__ void castsplit_k(const float* __restrict__ in, int N, int K,
                            unsigned short* __restrict__ hi, unsigned short* __restrict__ lo,
                            int Np, int Kp) {
    size_t gid = (size_t)blockIdx.x * 256 + threadIdx.x;
    if (gid >= (size_t)Np * Kp) return;
    int n = (int)(gid / Kp), k = (int)(gid % Kp);
    float v = (n < N && k < K) ? in[(size_t)n * K + k] : 0.0f;
    unsigned short hb = f2bf(v);
    hi[gid] = hb;
    lo[gid] = f2bf(v - bf2f(hb));
}

__global__ void transcast_k(const float* __restrict__ in, int R, int C,
                            unsigned short* __restrict__ out, int Rp, int Cp) {
    __shared__ float tile[32][33];
    int c0 = blockIdx.x * 32, r0 = blockIdx.y * 32;
    int tx = threadIdx.x & 31, ty = threadIdx.x >> 5;
    for (int i = 0; i < 4; i++) {
        int r = r0 + ty + i * 8, c = c0 + tx;
        tile[ty + i * 8][tx] = (r < R && c < C) ? in[(size_t)r * C + c] : 0.0f;
    }
    __syncthreads();
    for (int i = 0; i < 4; i++) {
        int c = c0 + ty + i * 8, r = r0 + tx;
        if (c < Cp && r < Rp) out[(size_t)c * Rp + r] = f2bf(tile[tx][ty + i * 8]);
    }
}

__global__ void biascomb_k(const float* a, const float* b, float* o, int realN, int Np) {
    int gid = blockIdx.x * 256 + threadIdx.x;
    if (gid >= Np) return;
    o[gid] = (gid < realN) ? a[gid] + b[gid] : 0.0f;
}

// ---------------- M=32 GEMM plain bf16, k-split partials ----------------
__global__ __launch_bounds__(256) void gemm32_k(const unsigned short* __restrict__ A,
                                                const unsigned short* __restrict__ W,
                                                float* __restrict__ part,
                                                int Kld, int Np, int ksteps, int slot_base) {
    int n0 = blockIdx.x * 64;
    int kb = blockIdx.y;
    int k0 = kb * ksteps * 32;
    int wid = threadIdx.x >> 6, lane = threadIdx.x & 63;
    int r = lane & 15, kg = lane >> 4;
    const unsigned short* Wrow = W + (size_t)(n0 + wid * 16 + r) * Kld + k0 + kg * 8;
    const unsigned short* Ar0 = A + (size_t)r * Kld + k0 + kg * 8;
    const unsigned short* Ar1 = Ar0 + (size_t)16 * Kld;
    f4v acc0 = {0.f, 0.f, 0.f, 0.f}, acc1 = {0.f, 0.f, 0.f, 0.f};
#pragma unroll
    for (int s = 0; s < ksteps; s++) {
        s8v bf = *(const s8v*)(Wrow + s * 32);
        s8v a0 = *(const s8v*)(Ar0 + s * 32);
        s8v a1 = *(const s8v*)(Ar1 + s * 32);
        acc0 = MFMA(a0, bf, acc0);
        acc1 = MFMA(a1, bf, acc1);
    }
    int ncol = n0 + wid * 16 + r;
    float* p = part + (size_t)(slot_base + kb) * 32 * Np + ncol;
#pragma unroll
    for (int q = 0; q < 4; q++) {
        int m = kg * 4 + q;
        p[(size_t)m * Np]        = acc0[q];
        p[(size_t)(m + 16) * Np] = acc1[q];
    }
}

__global__ void epi_k(const float* __restrict__ part, int nslots, int Np, int realN,
                      const float* __restrict__ bias, int act,
                      unsigned short* __restrict__ outbf) {
    int gid = blockIdx.x * 256 + threadIdx.x;
    int b = gid / Np, n = gid % Np;
    float v = 0.0f;
    if (n < realN) {
        v = bias ? bias[n] : 0.0f;
        for (int s = 0; s < nslots; s++) v += part[(size_t)(s * 32 + b) * Np + n];
        if (act) v = tanhf(v);
    }
    outbf[(size_t)b * Np + n] = f2bf(v);
}

__global__ void qbk_k(const unsigned short* __restrict__ q, int Kp, int realK,
                      const float* __restrict__ bk, float* __restrict__ out) {
    int b = blockIdx.x, tid = threadIdx.x;
    float s = 0.f;
    for (int d = tid; d < realK; d += 256) s += bf2f(q[(size_t)b * Kp + d]) * bk[d];
    for (int o = 32; o; o >>= 1) s += __shfl_xor(s, o);
    __shared__ float r[4];
    if ((tid & 63) == 0) r[tid >> 6] = s;
    __syncthreads();
    if (tid == 0) out[b] = r[0] + r[1] + r[2] + r[3];
}

__global__ void scores_k(const unsigned short* __restrict__ hs, const unsigned short* __restrict__ qk,
                         const float* __restrict__ qbk, float* __restrict__ out,
                         int Kp, float scale) {
    int gid = blockIdx.x * 4 + (threadIdx.x >> 6);
    int lane = threadIdx.x & 63;
    int b = gid >> 9, t = gid & 511;
    const unsigned short* hrow = hs + (size_t)(t * BB + b) * Kp;
    const unsigned short* qrow = qk + (size_t)b * Kp;
    float acc = 0.f;
    for (int kb = lane * 4; kb < Kp; kb += 256) {
        uint2 hv = *reinterpret_cast<const uint2*>(hrow + kb);
        uint2 qv = *reinterpret_cast<const uint2*>(qrow + kb);
        acc += __uint_as_float(hv.x << 16) * __uint_as_float(qv.x << 16);
        acc += __uint_as_float(hv.x & 0xFFFF0000u) * __uint_as_float(qv.x & 0xFFFF0000u);
        acc += __uint_as_float(hv.y << 16) * __uint_as_float(qv.y << 16);
        acc += __uint_as_float(hv.y & 0xFFFF0000u) * __uint_as_float(qv.y & 0xFFFF0000u);
    }
    for (int o = 32; o; o >>= 1) acc += __shfl_xor(acc, o);
    if (lane == 0) out[b * TT + t] = (acc + qbk[b]) * scale;
}

__global__ void softmax_k(const float* __restrict__ in, float* __restrict__ out) {
    int b = blockIdx.x, tid = threadIdx.x;
    float v0 = in[b * TT + tid], v1 = in[b * TT + 256 + tid];
    float mx = fmaxf(v0, v1);
    for (int o = 32; o; o >>= 1) mx = fmaxf(mx, __shfl_xor(mx, o));
    __shared__ float r[4], r2[4];
    int wid = tid >> 6, lane = tid & 63;
    if (lane == 0) r[wid] = mx;
    __syncthreads();
    mx = fmaxf(fmaxf(r[0], r[1]), fmaxf(r[2], r[3]));
    float e0 = expf(v0 - mx), e1 = expf(v1 - mx);
    float s = e0 + e1;
    for (int o = 32; o; o >>= 1) s += __shfl_xor(s, o);
    if (lane == 0) r2[wid] = s;
    __syncthreads();
    s = r2[0] + r2[1] + r2[2] + r2[3];
    float invs = 1.0f / s;
    out[b * TT + tid] = e0 * invs;
    out[b * TT + 256 + tid] = e1 * invs;
}

__global__ void attnsum_k(const unsigned short* __restrict__ hs, const float* __restrict__ aw,
                          unsigned short* __restrict__ out, int Kp) {
    int gid = blockIdx.x * 256 + threadIdx.x;
    int b = gid / Kp, e = gid % Kp;
    float acc = 0.f;
    for (int t = 0; t < TT; t++)
        acc += aw[b * TT + t] * bf2f(hs[((size_t)t * BB + b) * Kp + e]);
    out[(size_t)b * Kp + e] = f2bf(acc);
}

__global__ void cls_k(const unsigned short* __restrict__ h2f, const float* __restrict__ wcls,
                      const float* __restrict__ bcls, float* __restrict__ out) {
    int b = blockIdx.x;
    int wid = threadIdx.x >> 6, lane = threadIdx.x & 63;
    for (int o = wid; o < OO; o += 4) {
        float s = 0.f;
        for (int e = lane; e < EE; e += 64)
            s += bf2f(h2f[(size_t)b * EE + e]) * wcls[o * EE + e];
        for (int off = 32; off; off >>= 1) s += __shfl_xor(s, off);
        if (lane == 0) out[b * OO + o] = s + bcls[o];
    }
}

__global__ void fail_k(float* out) {
    int i = blockIdx.x * 256 + threadIdx.x;
    if (i < BB * OO) out[i] = 1e9f;
}

// =====================================================================
extern "C" void kernel_launch(void* const* d_in, const int* in_sizes, int n_in,
                              void* d_out, int out_size, void* d_ws, size_t ws_size,
                              hipStream_t stream) {
    const float* x        = (const float*)d_in[0];
    const float* in_g     = (const float*)d_in[1];
    const float* in_b     = (const float*)d_in[2];
    const float* w_ih1    = (const float*)d_in[3];
    const float* w_hh1    = (const float*)d_in[4];
    const float* b_ih1    = (const float*)d_in[5];
    const float* b_hh1    = (const float*)d_in[6];
    const float* ln1_g    = (const float*)d_in[7];
    const float* ln1_b    = (const float*)d_in[8];
    const float* w_ih2    = (const float*)d_in[9];
    const float* w_hh2    = (const float*)d_in[10];
    const float* b_ih2    = (const float*)d_in[11];
    const float* b_hh2    = (const float*)d_in[12];
    const float* m1_wqkv  = (const float*)d_in[13];
    const float* m1_bqkv  = (const float*)d_in[14];
    const float* m1_wo    = (const float*)d_in[15];
    const float* m1_bo    = (const float*)d_in[16];
    const float* m2_wqkv  = (const float*)d_in[17];
    const float* m2_bqkv  = (const float*)d_in[18];
    const float* m2_wo    = (const float*)d_in[19];
    const float* m2_bo    = (const float*)d_in[20];
    const float* w_cls    = (const float*)d_in[21];
    const float* b_cls    = (const float*)d_in[22];
    float* out = (float*)d_out;

    const size_t TB = (size_t)TT * BB;
    size_t cur = 0;
    auto alloc = [&](size_t bytes) { cur = (cur + 255) & ~(size_t)255; size_t o = cur; cur += bytes; return o; };
    char* ws = (char*)d_ws;
    #define US(off) ((unsigned short*)(ws + (off)))
    #define FP(off) ((float*)(ws + (off)))

    size_t o_xnhi   = alloc(TB * EE * 2);
    size_t o_xnlo   = alloc(TB * EE * 2);
    size_t o_wih1hi = alloc((size_t)HP * EE * 2);
    size_t o_wih1lo = alloc((size_t)HP * EE * 2);
    size_t o_whh1hi = alloc((size_t)HP * HP * 2);
    size_t o_whh1lo = alloc((size_t)HP * HP * 2);
    size_t o_wih2   = alloc((size_t)EE * HP * 2);
    size_t o_whh2   = alloc((size_t)EE * EE * 2);
    size_t o_h1s    = alloc(TB * HP * 2);
    size_t o_h2s    = alloc(TB * EE * 2);
    size_t o_v      = alloc((size_t)BB * HP * 4);
    size_t o_stats  = alloc((size_t)BB * 16 * 2 * 4);
    size_t o_h2hi   = alloc((size_t)BB * EE * 2);
    size_t o_h2lo   = alloc((size_t)BB * EE * 2);
    size_t o_part1  = alloc((size_t)SLOT1 * BB * HP * 4);
    size_t o_part2  = alloc((size_t)SLOT2 * BB * EE * 4);
    size_t o_b1c    = alloc((size_t)HP * 4);
    size_t o_b2c    = alloc((size_t)EE * 4);
    size_t o_cnt    = alloc(256);
    size_t o_wq1    = alloc((size_t)HP * HP * 2);
    size_t o_wk1T   = alloc((size_t)HP * HP * 2);
    size_t o_wv1    = alloc((size_t)HP * HP * 2);
    size_t o_wo1    = alloc((size_t)HP * HP * 2);
    size_t o_wq2    = alloc((size_t)EE * EE * 2);
    size_t o_wk2T   = alloc((size_t)EE * EE * 2);
    size_t o_wv2    = alloc((size_t)EE * EE * 2);
    size_t o_wo2    = alloc((size_t)EE * EE * 2);
    size_t o_q1     = alloc((size_t)BB * HP * 2);
    size_t o_qk1    = alloc((size_t)BB * HP * 2);
    size_t o_u1     = alloc((size_t)BB * HP * 2);
    size_t o_vc1    = alloc((size_t)BB * HP * 2);
    size_t o_ctx1   = alloc((size_t)BB * HP * 2);
    size_t o_qbk1   = alloc(BB * 4);
    size_t o_sc1    = alloc((size_t)BB * TT * 4);
    size_t o_aw1    = alloc((size_t)BB * TT * 4);
    size_t o_q2     = alloc((size_t)BB * EE * 2);
    size_t o_qk2    = alloc((size_t)BB * EE * 2);
    size_t o_u2     = alloc((size_t)BB * EE * 2);
    size_t o_vc2    = alloc((size_t)BB * EE * 2);
    size_t o_ctx2   = alloc((size_t)BB * EE * 2);
    size_t o_qbk2   = alloc(BB * 4);
    size_t o_sc2    = alloc((size_t)BB * TT * 4);
    size_t o_aw2    = alloc((size_t)BB * TT * 4);
    size_t o_h1f    = alloc((size_t)BB * HP * 2);
    size_t o_h2f    = alloc((size_t)BB * EE * 2);

    if (ws_size < cur) {
        fail_k<<<3, 256, 0, stream>>>(out);
        return;
    }

    // ---------- prep ----------
    ln_x_k<<<BB * TT, 256, 0, stream>>>(x, in_g, in_b, US(o_xnhi), US(o_xnlo));
    castsplit_k<<<(HP * EE + 255) / 256, 256, 0, stream>>>(w_ih1, HH, EE, US(o_wih1hi), US(o_wih1lo), HP, EE);
    castsplit_k<<<(HP * HP + 255) / 256, 256, 0, stream>>>(w_hh1, HH, HH, US(o_whh1hi), US(o_whh1lo), HP, HP);
    castpad_k<<<(EE * HP + 255) / 256, 256, 0, stream>>>(w_ih2, EE, HH, US(o_wih2), EE, HP);
    castpad_k<<<(EE * EE + 255) / 256, 256, 0, stream>>>(w_hh2, EE, EE, US(o_whh2), EE, EE);
    biascomb_k<<<(HP + 255) / 256, 256, 0, stream>>>(b_ih1, b_hh1, FP(o_b1c), HH, HP);
    biascomb_k<<<(EE + 255) / 256, 256, 0, stream>>>(b_ih2, b_hh2, FP(o_b2c), EE, EE);
    castpad_k<<<(HP * HP + 255) / 256, 256, 0, stream>>>(m1_wqkv, HH, HH, US(o_wq1), HP, HP);
    castpad_k<<<(HP * HP + 255) / 256, 256, 0, stream>>>(m1_wqkv + (size_t)2 * HH * HH, HH, HH, US(o_wv1), HP, HP);
    castpad_k<<<(HP * HP + 255) / 256, 256, 0, stream>>>(m1_wo, HH, HH, US(o_wo1), HP, HP);
    transcast_k<<<dim3(HP / 32, HP / 32), 256, 0, stream>>>(m1_wqkv + (size_t)HH * HH, HH, HH, US(o_wk1T), HP, HP);
    castpad_k<<<(EE * EE + 255) / 256, 256, 0, stream>>>(m2_wqkv, EE, EE, US(o_wq2), EE, EE);
    castpad_k<<<(EE * EE + 255) / 256, 256, 0, stream>>>(m2_wqkv + (size_t)2 * EE * EE, EE, EE, US(o_wv2), EE, EE);
    castpad_k<<<(EE * EE + 255) / 256, 256, 0, stream>>>(m2_wo, EE, EE, US(o_wo2), EE, EE);
    transcast_k<<<dim3(EE / 32, EE / 32), 256, 0, stream>>>(m2_wqkv + (size_t)EE * EE, EE, EE, US(o_wk2T), EE, EE);
    hipMemsetAsync(US(o_h2hi), 0, (size_t)BB * EE * 2, stream);
    hipMemsetAsync(US(o_h2lo), 0, (size_t)BB * EE * 2, stream);
    hipMemsetAsync(ws + o_cnt, 0, 256, stream);

    // ---------- persistent RNN loop ----------
    PP pp;
    pp.xnhi = US(o_xnhi); pp.xnlo = US(o_xnlo);
    pp.wih1hi = US(o_wih1hi); pp.wih1lo = US(o_wih1lo);
    pp.whh1hi = US(o_whh1hi); pp.whh1lo = US(o_whh1lo);
    pp.wih2 = US(o_wih2); pp.whh2 = US(o_whh2);
    pp.b1c = FP(o_b1c); pp.b2c = FP(o_b2c); pp.g1 = ln1_g; pp.be1 = ln1_b;
    pp.v = FP(o_v); pp.stats = FP(o_stats);
    pp.h2hi = US(o_h2hi); pp.h2lo = US(o_h2lo);
    pp.part1 = FP(o_part1); pp.part2 = FP(o_part2);
    pp.h1s = US(o_h1s); pp.h2s = US(o_h2s);
    pp.cnt = (unsigned int*)(ws + o_cnt);
    persist_k<<<NBLK, NTHR, 0, stream>>>(pp);

    const unsigned short* h1last = US(o_h1s) + (size_t)(TT - 1) * BB * HP;
    const unsigned short* h2last = US(o_h2s) + (size_t)(TT - 1) * BB * EE;
    const float sc_scale1 = 1.0f / sqrtf((float)HH);
    const float sc_scale2 = 1.0f / sqrtf((float)EE);

    // ---------- MHA1 (only last-row context needed) ----------
    gemm32_k<<<dim3(HP / 64, 7), 256, 0, stream>>>(h1last, US(o_wq1), FP(o_part1), HP, HP, 14, 0);
    epi_k<<<BB * HP / 256, 256, 0, stream>>>(FP(o_part1), 7, HP, HH, m1_bqkv, 0, US(o_q1));
    gemm32_k<<<dim3(HP / 64, 7), 256, 0, stream>>>(US(o_q1), US(o_wk1T), FP(o_part1), HP, HP, 14, 0);
    epi_k<<<BB * HP / 256, 256, 0, stream>>>(FP(o_part1), 7, HP, HH, nullptr, 0, US(o_qk1));
    qbk_k<<<BB, 256, 0, stream>>>(US(o_q1), HP, HH, m1_bqkv + HH, FP(o_qbk1));
    scores_k<<<BB * TT / 4, 256, 0, stream>>>(US(o_h1s), US(o_qk1), FP(o_qbk1), FP(o_sc1), HP, sc_scale1);
    softmax_k<<<BB, 256, 0, stream>>>(FP(o_sc1), FP(o_aw1));
    attnsum_k<<<BB * HP / 256, 256, 0, stream>>>(US(o_h1s), FP(o_aw1), US(o_u1), HP);
    gemm32_k<<<dim3(HP / 64, 7), 256, 0, stream>>>(US(o_u1), US(o_wv1), FP(o_part1), HP, HP, 14, 0);
    epi_k<<<BB * HP / 256, 256, 0, stream>>>(FP(o_part1), 7, HP, HH, m1_bqkv + 2 * HH, 0, US(o_vc1));
    gemm32_k<<<dim3(HP / 64, 7), 256, 0, stream>>>(US(o_vc1), US(o_wo1), FP(o_part1), HP, HP, 14, 0);
    epi_k<<<BB * HP / 256, 256, 0, stream>>>(FP(o_part1), 7, HP, HH, m1_bo, 0, US(o_ctx1));

    // ---------- MHA2 ----------
    gemm32_k<<<dim3(EE / 64, 3), 256, 0, stream>>>(h2last, US(o_wq2), FP(o_part2), EE, EE, 8, 0);
    epi_k<<<BB * EE / 256, 256, 0, stream>>>(FP(o_part2), 3, EE, EE, m2_bqkv, 0, US(o_q2));
    gemm32_k<<<dim3(EE / 64, 3), 256, 0, stream>>>(US(o_q2), US(o_wk2T), FP(o_part2), EE, EE, 8, 0);
    epi_k<<<BB * EE / 256, 256, 0, stream>>>(FP(o_part2), 3, EE, EE, nullptr, 0, US(o_qk2));
    qbk_k<<<BB, 256, 0, stream>>>(US(o_q2), EE, EE, m2_bqkv + EE, FP(o_qbk2));
    scores_k<<<BB * TT / 4, 256, 0, stream>>>(US(o_h2s), US(o_qk2), FP(o_qbk2), FP(o_sc2), EE, sc_scale2);
    softmax_k<<<BB, 256, 0, stream>>>(FP(o_sc2), FP(o_aw2));
    attnsum_k<<<BB * EE / 256, 256, 0, stream>>>(US(o_h2s), FP(o_aw2), US(o_u2), EE);
    gemm32_k<<<dim3(EE / 64, 3), 256, 0, stream>>>(US(o_u2), US(o_wv2), FP(o_part2), EE, EE, 8, 0);
    epi_k<<<BB * EE / 256, 256, 0, stream>>>(FP(o_part2), 3, EE, EE, m2_bqkv + 2 * EE, 0, US(o_vc2));
    gemm32_k<<<dim3(EE / 64, 3), 256, 0, stream>>>(US(o_vc2), US(o_wo2), FP(o_part2), EE, EE, 8, 0);
    epi_k<<<BB * EE / 256, 256, 0, stream>>>(FP(o_part2), 3, EE, EE, m2_bo, 0, US(o_ctx2));

    // ---------- final cells ----------
    const unsigned short* xnlast = US(o_xnhi) + (size_t)(TT - 1) * BB * EE;
    gemm32_k<<<dim3(HP / 64, 1), 256, 0, stream>>>(xnlast, US(o_wih1hi), FP(o_part1), EE, HP, EE / 32, 0);
    gemm32_k<<<dim3(HP / 64, 7), 256, 0, stream>>>(US(o_ctx1), US(o_whh1hi), FP(o_part1), HP, HP, 14, 1);
    epi_k<<<BB * HP / 256, 256, 0, stream>>>(FP(o_part1), 8, HP, HH, FP(o_b1c), 1, US(o_h1f));
    gemm32_k<<<dim3(EE / 64, 7), 256, 0, stream>>>(US(o_h1f), US(o_wih2), FP(o_part2), HP, EE, 14, 0);
    gemm32_k<<<dim3(EE / 64, 1), 256, 0, stream>>>(US(o_ctx2), US(o_whh2), FP(o_part2), EE, EE, EE / 32, 7);
    epi_k<<<BB * EE / 256, 256, 0, stream>>>(FP(o_part2), 8, EE, EE, FP(o_b2c), 1, US(o_h2f));
    cls_k<<<BB, 256, 0, stream>>>(US(o_h2f), w_cls, b_cls, out);
}

// Round 4
// 30524.335 us; speedup vs baseline: 6.7449x; 6.7449x over previous
//
#include <hip/hip_runtime.h>
#include <cstdint>
#include <cmath>

// ---------------- constants ----------------
#define BB 32
#define TT 512
#define EE 768
#define HH 3132
#define HP 3136   // H padded to mult of 64
#define OO 19

#define NBLK 512
#define NTHR 256
#define PITCH 472     // LDS row pitch in bf16 (944B = 59*16B, 59%8=3 coprime -> uniform bank slots)

// phase-A task bases (task = 511 - blk; blocks 0..23 idle in A)
#define B_T1X 343     // T1: 49 nt * 7 ks  (Whh1 @ h1n, split, 448-col LDS-staged slices)
#define B_T2  392     // T1x: 49 nt        (Wih1 @ xn[t], split, K=768 direct)
#define B_T3  476     // T2: 12 nt * 7 ks  (Wih2 @ h1n, hi, 448-col staged)
#define PA_TASKS 488  // T3: 12 nt         (Whh2 @ h2, split-A, K=768 direct sc1)

typedef __attribute__((ext_vector_type(8))) short s8v;
typedef __attribute__((ext_vector_type(4))) float f4v;

__device__ __forceinline__ unsigned short f2bf(float f) {
    uint32_t u = __float_as_uint(f);
    uint32_t r = u + 0x7FFFu + ((u >> 16) & 1u);
    return (unsigned short)(r >> 16);
}
__device__ __forceinline__ float bf2f(unsigned short h) {
    return __uint_as_float(((uint32_t)h) << 16);
}

#define MFMA(a, b, c) __builtin_amdgcn_mfma_f32_16x16x32_bf16((a), (b), (c), 0, 0, 0)

// ---- sc1 (device-scope, LLC-coherent, NO cache-invalidating fences) primitives ----
__device__ __forceinline__ f4v ld4_sc(const void* p) {
    f4v v;
    asm volatile("global_load_dwordx4 %0, %1, off sc0 sc1" : "=v"(v) : "v"(p) : "memory");
    return v;   // NOT valid until WAITV()
}
#define WAITV() do { asm volatile("s_waitcnt vmcnt(0)" ::: "memory"); \
                     __builtin_amdgcn_sched_barrier(0); } while (0)
__device__ __forceinline__ void st_sc(float* p, float v) {
    __hip_atomic_store(p, v, __ATOMIC_RELAXED, __HIP_MEMORY_SCOPE_AGENT);
}
__device__ __forceinline__ void st_scu(unsigned int* p, unsigned int v) {
    __hip_atomic_store(p, v, __ATOMIC_RELAXED, __HIP_MEMORY_SCOPE_AGENT);
}

// ---------------- persistent-kernel params ----------------
struct PP {
    const unsigned short *xnhi, *xnlo;
    const unsigned short *wih1hi, *wih1lo, *whh1hi, *whh1lo, *wih2, *whh2;
    const float *b1c, *b2c, *gpad, *bepad;
    unsigned short *h1nhi, *h1nlo;     // sc1: normalized h1 state hi/lo
    unsigned short *h2hi, *h2lo;       // sc1: h2 state hi/lo
    float *part1, *part2;              // sc1: [8][32][HP] / [8][32][EE]
    unsigned short *h1s, *h2s;         // normal: snapshots (read post-kernel)
    unsigned int *grp;                 // [64] stride 32 uints
    unsigned int *epoch;
};

// ---------------- relaxed hierarchical grid barrier (no fences, no L2 nukes) ----------------
__device__ __forceinline__ void gbar(const PP& p, unsigned int k) {
    __syncthreads();
    asm volatile("s_waitcnt vmcnt(0)" ::: "memory");   // sc1 stores visible at LLC before arrival
    if (threadIdx.x == 0)
        __hip_atomic_fetch_add(&p.grp[(blockIdx.x & 63) * 32], 1u,
                               __ATOMIC_RELAXED, __HIP_MEMORY_SCOPE_AGENT);
    if (blockIdx.x == 0) {
        if (threadIdx.x < 64) {
            unsigned int tgt = 8u * k;
            long g = 0;
            while (__hip_atomic_load(&p.grp[threadIdx.x * 32], __ATOMIC_RELAXED,
                                     __HIP_MEMORY_SCOPE_AGENT) < tgt) {
                __builtin_amdgcn_s_sleep(2);
                if (++g > (1L << 14)) break;   // watchdog: never hang
            }
        }
        __syncthreads();
        if (threadIdx.x == 0)
            __hip_atomic_store(p.epoch, k, __ATOMIC_RELAXED, __HIP_MEMORY_SCOPE_AGENT);
    } else {
        if (threadIdx.x == 0) {
            long g = 0;
            while (__hip_atomic_load(p.epoch, __ATOMIC_RELAXED,
                                     __HIP_MEMORY_SCOPE_AGENT) < k) {
                __builtin_amdgcn_s_sleep(2);
                if (++g > (1L << 14)) break;
            }
        }
    }
    __syncthreads();
}

// stage h1n [32][448] slice (sc1) into LDS; optionally lo matrix too
template<bool LO>
__device__ __forceinline__ void stageA(const PP& p, int k0,
                                       unsigned short (*Ah)[PITCH], unsigned short (*Al)[PITCH]) {
    const char* bh = (const char*)p.h1nhi;
    const char* bl = (const char*)p.h1nlo;
    const int tid = threadIdx.x;
    f4v hv[7], lv[7];
#pragma unroll
    for (int i = 0; i < 7; ++i) {
        int j = tid + i * 256, row = j / 56, c16 = j % 56;
        hv[i] = ld4_sc(bh + (size_t)row * (HP * 2) + k0 * 2 + c16 * 16);
    }
    if (LO) {
#pragma unroll
        for (int i = 0; i < 7; ++i) {
            int j = tid + i * 256, row = j / 56, c16 = j % 56;
            lv[i] = ld4_sc(bl + (size_t)row * (HP * 2) + k0 * 2 + c16 * 16);
        }
    }
    WAITV();
#pragma unroll
    for (int i = 0; i < 7; ++i) {
        int j = tid + i * 256, row = j / 56, c16 = j % 56;
        *(f4v*)&Ah[row][c16 * 8] = hv[i];
        if (LO) *(f4v*)&Al[row][c16 * 8] = lv[i];
    }
    __syncthreads();
}

__global__ __launch_bounds__(NTHR, 2) void persist_k(PP p) {
    __shared__ unsigned short Ah[32][PITCH];
    __shared__ unsigned short Al[32][PITCH];
    __shared__ float redS[4], redQ[4];
    const int blk = blockIdx.x, tid = threadIdx.x;
    const int wid = tid >> 6, lane = tid & 63;
    const int r = lane & 15, kg = lane >> 4;
    const int task = 511 - blk;     // block 0 (barrier finalizer) idle in phase A
    unsigned int bar = 0;

    for (int t = 0; t <= TT; ++t) {
        // ===================== PHASE A: GEMMs =====================
        if (task < B_T1X) {
            // ---- T1: part1[ks] = Whh1 @ h1n[t-1] (split precision) ----
            if (t >= 1 && t < TT) {
                int nt = task / 7, ks = task % 7;
                int n0 = nt * 64, k0 = ks * 448;
                stageA<true>(p, k0, Ah, Al);
                const unsigned short* Whr = p.whh1hi + (size_t)(n0 + wid * 16 + r) * HP + k0 + kg * 8;
                const unsigned short* Wlr = p.whh1lo + (size_t)(n0 + wid * 16 + r) * HP + k0 + kg * 8;
                f4v acc0 = {0.f, 0.f, 0.f, 0.f}, acc1 = {0.f, 0.f, 0.f, 0.f};
#pragma unroll
                for (int s = 0; s < 14; ++s) {
                    s8v bh  = *(const s8v*)(Whr + s * 32);
                    s8v bl  = *(const s8v*)(Wlr + s * 32);
                    s8v a0h = *(const s8v*)&Ah[r][kg * 8 + s * 32];
                    s8v a1h = *(const s8v*)&Ah[r + 16][kg * 8 + s * 32];
                    s8v a0l = *(const s8v*)&Al[r][kg * 8 + s * 32];
                    s8v a1l = *(const s8v*)&Al[r + 16][kg * 8 + s * 32];
                    acc0 = MFMA(a0h, bh, acc0); acc1 = MFMA(a1h, bh, acc1);
                    acc0 = MFMA(a0l, bh, acc0); acc1 = MFMA(a1l, bh, acc1);
                    acc0 = MFMA(a0h, bl, acc0); acc1 = MFMA(a1h, bl, acc1);
                }
                int ncol = n0 + wid * 16 + r;
                float* pp1 = p.part1 + (size_t)ks * BB * HP + ncol;
#pragma unroll
                for (int q = 0; q < 4; ++q) {
                    st_sc(pp1 + (size_t)(kg * 4 + q) * HP,        acc0[q]);
                    st_sc(pp1 + (size_t)(kg * 4 + q + 16) * HP,   acc1[q]);
                }
            }
        } else if (task < B_T2) {
            // ---- T1x: part1[7] = Wih1 @ xn[t] (split, K=768, normal loads) ----
            if (t < TT) {
                int nt = task - B_T1X, n0 = nt * 64;
                const unsigned short* A0h = p.xnhi + ((size_t)t * BB + r) * EE + kg * 8;
                const unsigned short* A1h = A0h + (size_t)16 * EE;
                const unsigned short* A0l = p.xnlo + ((size_t)t * BB + r) * EE + kg * 8;
                const unsigned short* A1l = A0l + (size_t)16 * EE;
                const unsigned short* Whr = p.wih1hi + (size_t)(n0 + wid * 16 + r) * EE + kg * 8;
                const unsigned short* Wlr = p.wih1lo + (size_t)(n0 + wid * 16 + r) * EE + kg * 8;
                f4v acc0 = {0.f, 0.f, 0.f, 0.f}, acc1 = {0.f, 0.f, 0.f, 0.f};
#pragma unroll 6
                for (int s = 0; s < 24; ++s) {
                    s8v bh  = *(const s8v*)(Whr + s * 32);
                    s8v bl  = *(const s8v*)(Wlr + s * 32);
                    s8v a0h = *(const s8v*)(A0h + s * 32);
                    s8v a1h = *(const s8v*)(A1h + s * 32);
                    s8v a0l = *(const s8v*)(A0l + s * 32);
                    s8v a1l = *(const s8v*)(A1l + s * 32);
                    acc0 = MFMA(a0h, bh, acc0); acc1 = MFMA(a1h, bh, acc1);
                    acc0 = MFMA(a0l, bh, acc0); acc1 = MFMA(a1l, bh, acc1);
                    acc0 = MFMA(a0h, bl, acc0); acc1 = MFMA(a1h, bl, acc1);
                }
                int ncol = n0 + wid * 16 + r;
                float* pp1 = p.part1 + (size_t)7 * BB * HP + ncol;
#pragma unroll
                for (int q = 0; q < 4; ++q) {
                    st_sc(pp1 + (size_t)(kg * 4 + q) * HP,      acc0[q]);
                    st_sc(pp1 + (size_t)(kg * 4 + q + 16) * HP, acc1[q]);
                }
            }
        } else if (task < B_T3) {
            // ---- T2: part2[ks] = Wih2 @ h1n[t-1] (hi only) ----
            if (t >= 1) {
                int id = task - B_T2;
                int nt = id / 7, ks = id % 7;
                int n0 = nt * 64, k0 = ks * 448;
                stageA<false>(p, k0, Ah, Al);
                const unsigned short* Whr = p.wih2 + (size_t)(n0 + wid * 16 + r) * HP + k0 + kg * 8;
                f4v acc0 = {0.f, 0.f, 0.f, 0.f}, acc1 = {0.f, 0.f, 0.f, 0.f};
#pragma unroll
                for (int s = 0; s < 14; ++s) {
                    s8v bh  = *(const s8v*)(Whr + s * 32);
                    s8v a0h = *(const s8v*)&Ah[r][kg * 8 + s * 32];
                    s8v a1h = *(const s8v*)&Ah[r + 16][kg * 8 + s * 32];
                    acc0 = MFMA(a0h, bh, acc0); acc1 = MFMA(a1h, bh, acc1);
                }
                int ncol = n0 + wid * 16 + r;
                float* pp2 = p.part2 + (size_t)ks * BB * EE + ncol;
#pragma unroll
                for (int q = 0; q < 4; ++q) {
                    st_sc(pp2 + (size_t)(kg * 4 + q) * EE,      acc0[q]);
                    st_sc(pp2 + (size_t)(kg * 4 + q + 16) * EE, acc1[q]);
                }
            }
        } else if (task < PA_TASKS) {
            // ---- T3: part2[7] = Whh2 @ h2state (split A via sc1, hi W) ----
            if (t >= 1) {
                int nt = task - B_T3, n0 = nt * 64;
                const unsigned short* Whr = p.whh2 + (size_t)(n0 + wid * 16 + r) * EE + kg * 8;
                const char* Hh = (const char*)p.h2hi;
                const char* Hl = (const char*)p.h2lo;
                size_t ro0 = (size_t)r * (EE * 2) + kg * 16;
                size_t ro1 = (size_t)(r + 16) * (EE * 2) + kg * 16;
                f4v acc0 = {0.f, 0.f, 0.f, 0.f}, acc1 = {0.f, 0.f, 0.f, 0.f};
#pragma unroll
                for (int c = 0; c < 4; ++c) {
                    f4v v0h[6], v1h[6], v0l[6], v1l[6];
#pragma unroll
                    for (int u = 0; u < 6; ++u) {
                        int off = (c * 6 + u) * 64;
                        v0h[u] = ld4_sc(Hh + ro0 + off);
                        v1h[u] = ld4_sc(Hh + ro1 + off);
                        v0l[u] = ld4_sc(Hl + ro0 + off);
                        v1l[u] = ld4_sc(Hl + ro1 + off);
                    }
                    WAITV();
#pragma unroll
                    for (int u = 0; u < 6; ++u) {
                        int s = c * 6 + u;
                        s8v bh = *(const s8v*)(Whr + s * 32);
                        acc0 = MFMA(__builtin_bit_cast(s8v, v0h[u]), bh, acc0);
                        acc0 = MFMA(__builtin_bit_cast(s8v, v0l[u]), bh, acc0);
                        acc1 = MFMA(__builtin_bit_cast(s8v, v1h[u]), bh, acc1);
                        acc1 = MFMA(__builtin_bit_cast(s8v, v1l[u]), bh, acc1);
                    }
                }
                int ncol = n0 + wid * 16 + r;
                float* pp2 = p.part2 + (size_t)7 * BB * EE + ncol;
#pragma unroll
                for (int q = 0; q < 4; ++q) {
                    st_sc(pp2 + (size_t)(kg * 4 + q) * EE,      acc0[q]);
                    st_sc(pp2 + (size_t)(kg * 4 + q + 16) * EE, acc1[q]);
                }
            }
        }
        gbar(p, ++bar);

        // ===================== PHASE B: pointwise =====================
        if (blk >= 448 && blk < 480) {
            // ---- U1: full-row h1: reduce + tanh + LN stats + normalize + split + snapshot ----
            if (t < TT) {
                int b = blk - 448;
                bool act = tid < 196;
                int nb = tid * 16;
                float acc[16];
                float s = 0.f, s2 = 0.f;
                if (act) {
#pragma unroll
                    for (int k4 = 0; k4 < 4; ++k4) {
                        f4v bb = *(const f4v*)(p.b1c + nb + k4 * 4);
#pragma unroll
                        for (int e = 0; e < 4; ++e) acc[k4 * 4 + e] = bb[e];
                    }
#pragma unroll
                    for (int half = 0; half < 2; ++half) {
                        f4v tmp[16];
#pragma unroll
                        for (int s4 = 0; s4 < 4; ++s4) {
                            int slot = half * 4 + s4;
                            const float* base = p.part1 + ((size_t)slot * BB + b) * HP + nb;
#pragma unroll
                            for (int k4 = 0; k4 < 4; ++k4)
                                tmp[s4 * 4 + k4] = ld4_sc(base + k4 * 4);
                        }
                        WAITV();
#pragma unroll
                        for (int s4 = 0; s4 < 4; ++s4) {
                            int slot = half * 4 + s4;
                            float w = (t == 0 && slot < 7) ? 0.f : 1.f;   // T1 slots stale at t==0
#pragma unroll
                            for (int k4 = 0; k4 < 4; ++k4)
#pragma unroll
                                for (int e = 0; e < 4; ++e)
                                    acc[k4 * 4 + e] += w * tmp[s4 * 4 + k4][e];
                        }
                    }
#pragma unroll
                    for (int j = 0; j < 16; ++j) {
                        if (nb + j < HH) {
                            float v = tanhf(acc[j]);
                            acc[j] = v; s += v; s2 += v * v;
                        } else acc[j] = 0.f;
                    }
                }
                for (int o = 32; o; o >>= 1) { s += __shfl_xor(s, o); s2 += __shfl_xor(s2, o); }
                if (lane == 0) { redS[wid] = s; redQ[wid] = s2; }
                __syncthreads();
                float S  = redS[0] + redS[1] + redS[2] + redS[3];
                float S2 = redQ[0] + redQ[1] + redQ[2] + redQ[3];
                float m = S / (float)HH;
                float inv = rsqrtf(S2 / (float)HH - m * m + 1e-5f);
                __syncthreads();
                if (act) {
#pragma unroll
                    for (int k4 = 0; k4 < 4; ++k4) {
                        f4v gv = *(const f4v*)(p.gpad + nb + k4 * 4);
                        f4v bv = *(const f4v*)(p.bepad + nb + k4 * 4);
                        unsigned short hb[4], lb[4];
#pragma unroll
                        for (int e = 0; e < 4; ++e) {
                            int n = nb + k4 * 4 + e;
                            float o = (n < HH) ? (acc[k4 * 4 + e] - m) * inv * gv[e] + bv[e] : 0.f;
                            hb[e] = f2bf(o);
                            lb[e] = f2bf(o - bf2f(hb[e]));
                        }
                        unsigned int h0 = (unsigned)hb[0] | ((unsigned)hb[1] << 16);
                        unsigned int h1 = (unsigned)hb[2] | ((unsigned)hb[3] << 16);
                        unsigned int l0 = (unsigned)lb[0] | ((unsigned)lb[1] << 16);
                        unsigned int l1 = (unsigned)lb[2] | ((unsigned)lb[3] << 16);
                        unsigned int* dh = (unsigned int*)(p.h1nhi + (size_t)b * HP + nb + k4 * 4);
                        unsigned int* dl = (unsigned int*)(p.h1nlo + (size_t)b * HP + nb + k4 * 4);
                        st_scu(dh, h0); st_scu(dh + 1, h1);
                        st_scu(dl, l0); st_scu(dl + 1, l1);
                        unsigned int* ds = (unsigned int*)(p.h1s + ((size_t)t * BB + b) * HP + nb + k4 * 4);
                        ds[0] = h0; ds[1] = h1;     // normal store (read post-kernel)
                    }
                }
            }
        } else if (blk >= 480) {
            // ---- U2: h2 row: reduce + tanh + split + snapshot ----
            if (t >= 1) {
                int b = blk - 480;
                if (tid < 192) {
                    int nb = tid * 4;
                    f4v a4 = *(const f4v*)(p.b2c + nb);
                    f4v tmp[8];
#pragma unroll
                    for (int slot = 0; slot < 8; ++slot)
                        tmp[slot] = ld4_sc(p.part2 + ((size_t)slot * BB + b) * EE + nb);
                    WAITV();
#pragma unroll
                    for (int slot = 0; slot < 8; ++slot)
#pragma unroll
                        for (int e = 0; e < 4; ++e) a4[e] += tmp[slot][e];
                    unsigned short hb[4], lb[4];
#pragma unroll
                    for (int e = 0; e < 4; ++e) {
                        float v = tanhf(a4[e]);
                        hb[e] = f2bf(v);
                        lb[e] = f2bf(v - bf2f(hb[e]));
                    }
                    unsigned int h0 = (unsigned)hb[0] | ((unsigned)hb[1] << 16);
                    unsigned int h1 = (unsigned)hb[2] | ((unsigned)hb[3] << 16);
                    unsigned int l0 = (unsigned)lb[0] | ((unsigned)lb[1] << 16);
                    unsigned int l1 = (unsigned)lb[2] | ((unsigned)lb[3] << 16);
                    unsigned int* dh = (unsigned int*)(p.h2hi + (size_t)b * EE + nb);
                    unsigned int* dl = (unsigned int*)(p.h2lo + (size_t)b * EE + nb);
                    st_scu(dh, h0); st_scu(dh + 1, h1);
                    st_scu(dl, l0); st_scu(dl + 1, l1);
                    unsigned int* ds = (unsigned int*)(p.h2s + ((size_t)(t - 1) * BB + b) * EE + nb);
                    ds[0] = h0; ds[1] = h1;     // normal store
                }
            }
        }
        gbar(p, ++bar);
    }
}

// ---------------- prep kernels ----------------
__global__ void ln_x_k(const float* __restrict__ x, const float* __restrict__ g,
                       const float* __restrict__ be, unsigned short* __restrict__ xnhi,
                       unsigned short* __restrict__ xnlo) {
    int bt = blockIdx.x;
    int b = bt >> 9, t = bt & 511;
    const float* row = x + ((size_t)b * TT + t) * EE;
    int tid = threadIdx.x;
    float v0 = row[tid], v1 = row[tid + 256], v2 = row[tid + 512];
    float s = v0 + v1 + v2, s2 = v0 * v0 + v1 * v1 + v2 * v2;
    for (int o = 32; o; o >>= 1) { s += __shfl_xor(s, o); s2 += __shfl_xor(s2, o); }
    __shared__ float r1[4], r2[4];
    int wid = tid >> 6, lane = tid & 63;
    if (lane == 0) { r1[wid] = s; r2[wid] = s2; }
    __syncthreads();
    s = r1[0] + r1[1] + r1[2] + r1[3];
    s2 = r2[0] + r2[1] + r2[2] + r2[3];
    float m = s / (float)EE, var = s2 / (float)EE - m * m;
    float inv = rsqrtf(var + 1e-5f);
    size_t ro = ((size_t)t * BB + b) * EE;
    float vals[3] = {v0, v1, v2};
#pragma unroll
    for (int i = 0; i < 3; i++) {
        int e = tid + i * 256;
        float o = (vals[i] - m) * inv * g[e] + be[e];
        unsigned short hb = f2bf(o);
        xnhi[ro + e] = hb;
        xnlo[ro + e] = f2bf(o - bf2f(hb));
    }
}

__global__ void castpad_k(const float* __restrict__ in, int N, int K,
                          unsigned short* __restrict__ out, int Np, int Kp) {
    size_t gid = (size_t)blockIdx.x * 256 + threadIdx.x;
    if (gid >= (size_t)Np * Kp) return;
    int n = (int)(gid / Kp), k = (int)(gid % Kp);
    out[gid] = (n < N && k < K) ? f2bf(in[(size_t)n * K + k]) : (unsigned short)0;
}

__global__ void castsplit_k(const float* __restrict__ in, int N, int K,
                            unsigned short* __restrict__ hi, unsigned short* __restrict__ lo,
                            int Np, int Kp) {
    size_t gid = (size_t)blockIdx.x * 256 + threadIdx.x;
    if (gid >= (size_t)Np * Kp) return;
    int n = (int)(gid / Kp), k = (int)(gid % Kp);
    float v = (n < N && k < K) ? in[(size_t)n * K + k] : 0.0f;
    unsigned short hb = f2bf(v);
    hi[gid] = hb;
    lo[gid] = f2bf(v - bf2f(hb));
}

__global__ void transcast_k(const float* __restrict__ in, int R, int C,
                            unsigned short* __restrict__ out, int Rp, int Cp) {
    __shared__ float tile[32][33];
    int c0 = blockIdx.x * 32, r0 = blockIdx.y * 32;
    int tx = threadIdx.x & 31, ty = threadIdx.x >> 5;
    for (int i = 0; i < 4; i++) {
        int r = r0 + ty + i * 8, c = c0 + tx;
        tile[ty + i * 8][tx] = (r < R && c < C) ? in[(size_t)r * C + c] : 0.0f;
    }
    __syncthreads();
    for (int i = 0; i < 4; i++) {
        int c = c0 + ty + i * 8, r = r0 + tx;
        if (c < Cp && r < Rp) out[(size_t)c * Rp + r] = f2bf(tile[tx][ty + i * 8]);
    }
}

__global__ void biascomb_k(const float* a, const float* b, float* o, int realN, int Np) {
    int gid = blockIdx.x * 256 + threadIdx.x;
    if (gid >= Np) return;
    o[gid] = (gid < realN) ? a[gid] + b[gid] : 0.0f;
}

__global__ void padcopy_k(const float* in, float* out, int realN, int Np) {
    int gid = blockIdx.x * 256 + threadIdx.x;
    if (gid >= Np) return;
    out[gid] = (gid < realN) ? in[gid] : 0.0f;
}

// ---------------- tail kernels (post-recurrence, unchanged structure) ----------------
__global__ __launch_bounds__(256) void gemm32_k(const unsigned short* __restrict__ A,
                                                const unsigned short* __restrict__ W,
                                                float* __restrict__ part,
                                                int Kld, int Np, int ksteps, int slot_base) {
    int n0 = blockIdx.x * 64;
    int kb = blockIdx.y;
    int k0 = kb * ksteps * 32;
    int wid = threadIdx.x >> 6, lane = threadIdx.x & 63;
    int r = lane & 15, kg = lane >> 4;
    const unsigned short* Wrow = W + (size_t)(n0 + wid * 16 + r) * Kld + k0 + kg * 8;
    const unsigned short* Ar0 = A + (size_t)r * Kld + k0 + kg * 8;
    const unsigned short* Ar1 = Ar0 + (size_t)16 * Kld;
    f4v acc0 = {0.f, 0.f, 0.f, 0.f}, acc1 = {0.f, 0.f, 0.f, 0.f};
#pragma unroll
    for (int s = 0; s < ksteps; s++) {
        s8v bf = *(const s8v*)(Wrow + s * 32);
        s8v a0 = *(const s8v*)(Ar0 + s * 32);
        s8v a1 = *(const s8v*)(Ar1 + s * 32);
        acc0 = MFMA(a0, bf, acc0);
        acc1 = MFMA(a1, bf, acc1);
    }
    int ncol = n0 + wid * 16 + r;
    float* p = part + (size_t)(slot_base + kb) * 32 * Np + ncol;
#pragma unroll
    for (int q = 0; q < 4; q++) {
        int m = kg * 4 + q;
        p[(size_t)m * Np]        = acc0[q];
        p[(size_t)(m + 16) * Np] = acc1[q];
    }
}

__global__ void epi_k(const float* __restrict__ part, int nslots, int Np, int realN,
                      const float* __restrict__ bias, int act,
                      unsigned short* __restrict__ outbf) {
    int gid = blockIdx.x * 256 + threadIdx.x;
    int b = gid / Np, n = gid % Np;
    float v = 0.0f;
    if (n < realN) {
        v = bias ? bias[n] : 0.0f;
        for (int s = 0; s < nslots; s++) v += part[(size_t)(s * 32 + b) * Np + n];
        if (act) v = tanhf(v);
    }
    outbf[(size_t)b * Np + n] = f2bf(v);
}

__global__ void qbk_k(const unsigned short* __restrict__ q, int Kp, int realK,
                      const float* __restrict__ bk, float* __restrict__ out) {
    int b = blockIdx.x, tid = threadIdx.x;
    float s = 0.f;
    for (int d = tid; d < realK; d += 256) s += bf2f(q[(size_t)b * Kp + d]) * bk[d];
    for (int o = 32; o; o >>= 1) s += __shfl_xor(s, o);
    __shared__ float r[4];
    if ((tid & 63) == 0) r[tid >> 6] = s;
    __syncthreads();
    if (tid == 0) out[b] = r[0] + r[1] + r[2] + r[3];
}

__global__ void scores_k(const unsigned short* __restrict__ hs, const unsigned short* __restrict__ qk,
                         const float* __restrict__ qbk, float* __restrict__ out,
                         int Kp, float scale) {
    int gid = blockIdx.x * 4 + (threadIdx.x >> 6);
    int lane = threadIdx.x & 63;
    int b = gid >> 9, t = gid & 511;
    const unsigned short* hrow = hs + (size_t)(t * BB + b) * Kp;
    const unsigned short* qrow = qk + (size_t)b * Kp;
    float acc = 0.f;
    for (int kb = lane * 4; kb < Kp; kb += 256) {
        uint2 hv = *reinterpret_cast<const uint2*>(hrow + kb);
        uint2 qv = *reinterpret_cast<const uint2*>(qrow + kb);
        acc += __uint_as_float(hv.x << 16) * __uint_as_float(qv.x << 16);
        acc += __uint_as_float(hv.x & 0xFFFF0000u) * __uint_as_float(qv.x & 0xFFFF0000u);
        acc += __uint_as_float(hv.y << 16) * __uint_as_float(qv.y << 16);
        acc += __uint_as_float(hv.y & 0xFFFF0000u) * __uint_as_float(qv.y & 0xFFFF0000u);
    }
    for (int o = 32; o; o >>= 1) acc += __shfl_xor(acc, o);
    if (lane == 0) out[b * TT + t] = (acc + qbk[b]) * scale;
}

__global__ void softmax_k(const float* __restrict__ in, float* __restrict__ out) {
    int b = blockIdx.x, tid = threadIdx.x;
    float v0 = in[b * TT + tid], v1 = in[b * TT + 256 + tid];
    float mx = fmaxf(v0, v1);
    for (int o = 32; o; o >>= 1) mx = fmaxf(mx, __shfl_xor(mx, o));
    __shared__ float r[4], r2[4];
    int wid = tid >> 6, lane = tid & 63;
    if (lane == 0) r[wid] = mx;
    __syncthreads();
    mx = fmaxf(fmaxf(r[0], r[1]), fmaxf(r[2], r[3]));
    float e0 = expf(v0 - mx), e1 = expf(v1 - mx);
    float s = e0 + e1;
    for (int o = 32; o; o >>= 1) s += __shfl_xor(s, o);
    if (lane == 0) r2[wid] = s;
    __syncthreads();
    s = r2[0] + r2[1] + r2[2] + r2[3];
    float invs = 1.0f / s;
    out[b * TT + tid] = e0 * invs;
    out[b * TT + 256 + tid] = e1 * invs;
}

__global__ void attnsum_k(const unsigned short* __restrict__ hs, const float* __restrict__ aw,
                          unsigned short* __restrict__ out, int Kp) {
    int gid = blockIdx.x * 256 + threadIdx.x;
    int b = gid / Kp, e = gid % Kp;
    float acc = 0.f;
    for (int t = 0; t < TT; t++)
        acc += aw[b * TT + t] * bf2f(hs[((size_t)t * BB + b) * Kp + e]);
    out[(size_t)b * Kp + e] = f2bf(acc);
}

__global__ void cls_k(const unsigned short* __restrict__ h2f, const float* __restrict__ wcls,
                      const float* __restrict__ bcls, float* __restrict__ out) {
    int b = blockIdx.x;
    int wid = threadIdx.x >> 6, lane = threadIdx.x & 63;
    for (int o = wid; o < OO; o += 4) {
        float s = 0.f;
        for (int e = lane; e < EE; e += 64)
            s += bf2f(h2f[(size_t)b * EE + e]) * wcls[o * EE + e];
        for (int off = 32; off; off >>= 1) s += __shfl_xor(s, off);
        if (lane == 0) out[b * OO + o] = s + bcls[o];
    }
}

__global__ void fail_k(float* out) {
    int i = blockIdx.x * 256 + threadIdx.x;
    if (i < BB * OO) out[i] = 1e9f;
}

// =====================================================================
extern "C" void kernel_launch(void* const* d_in, const int* in_sizes, int n_in,
                              void* d_out, int out_size, void* d_ws, size_t ws_size,
                              hipStream_t stream) {
    const float* x        = (const float*)d_in[0];
    const float* in_g     = (const float*)d_in[1];
    const float* in_b     = (const float*)d_in[2];
    const float* w_ih1    = (const float*)d_in[3];
    const float* w_hh1    = (const float*)d_in[4];
    const float* b_ih1    = (const float*)d_in[5];
    const float* b_hh1    = (const float*)d_in[6];
    const float* ln1_g    = (const float*)d_in[7];
    const float* ln1_b    = (const float*)d_in[8];
    const float* w_ih2    = (const float*)d_in[9];
    const float* w_hh2    = (const float*)d_in[10];
    const float* b_ih2    = (const float*)d_in[11];
    const float* b_hh2    = (const float*)d_in[12];
    const float* m1_wqkv  = (const float*)d_in[13];
    const float* m1_bqkv  = (const float*)d_in[14];
    const float* m1_wo    = (const float*)d_in[15];
    const float* m1_bo    = (const float*)d_in[16];
    const float* m2_wqkv  = (const float*)d_in[17];
    const float* m2_bqkv  = (const float*)d_in[18];
    const float* m2_wo    = (const float*)d_in[19];
    const float* m2_bo    = (const float*)d_in[20];
    const float* w_cls    = (const float*)d_in[21];
    const float* b_cls    = (const float*)d_in[22];
    float* out = (float*)d_out;

    const size_t TB = (size_t)TT * BB;
    size_t cur = 0;
    auto alloc = [&](size_t bytes) { cur = (cur + 255) & ~(size_t)255; size_t o = cur; cur += bytes; return o; };
    char* ws = (char*)d_ws;
    #define US(off) ((unsigned short*)(ws + (off)))
    #define FP(off) ((float*)(ws + (off)))

    size_t o_xnhi   = alloc(TB * EE * 2);
    size_t o_xnlo   = alloc(TB * EE * 2);
    size_t o_wih1hi = alloc((size_t)HP * EE * 2);
    size_t o_wih1lo = alloc((size_t)HP * EE * 2);
    size_t o_whh1hi = alloc((size_t)HP * HP * 2);
    size_t o_whh1lo = alloc((size_t)HP * HP * 2);
    size_t o_wih2   = alloc((size_t)EE * HP * 2);
    size_t o_whh2   = alloc((size_t)EE * EE * 2);
    size_t o_h1s    = alloc(TB * HP * 2);
    size_t o_h2s    = alloc(TB * EE * 2);
    size_t o_h1nhi  = alloc((size_t)BB * HP * 2);
    size_t o_h1nlo  = alloc((size_t)BB * HP * 2);
    size_t o_h2hi   = alloc((size_t)BB * EE * 2);
    size_t o_h2lo   = alloc((size_t)BB * EE * 2);
    size_t o_part1  = alloc((size_t)8 * BB * HP * 4);
    size_t o_part2  = alloc((size_t)8 * BB * EE * 4);
    size_t o_b1c    = alloc((size_t)HP * 4);
    size_t o_b2c    = alloc((size_t)EE * 4);
    size_t o_gpad   = alloc((size_t)HP * 4);
    size_t o_bepad  = alloc((size_t)HP * 4);
    size_t o_sync   = alloc(64 * 128 + 256);      // grp[64] @128B stride + epoch
    size_t o_wq1    = alloc((size_t)HP * HP * 2);
    size_t o_wk1T   = alloc((size_t)HP * HP * 2);
    size_t o_wv1    = alloc((size_t)HP * HP * 2);
    size_t o_wo1    = alloc((size_t)HP * HP * 2);
    size_t o_wq2    = alloc((size_t)EE * EE * 2);
    size_t o_wk2T   = alloc((size_t)EE * EE * 2);
    size_t o_wv2    = alloc((size_t)EE * EE * 2);
    size_t o_wo2    = alloc((size_t)EE * EE * 2);
    size_t o_q1     = alloc((size_t)BB * HP * 2);
    size_t o_qk1    = alloc((size_t)BB * HP * 2);
    size_t o_u1     = alloc((size_t)BB * HP * 2);
    size_t o_vc1    = alloc((size_t)BB * HP * 2);
    size_t o_ctx1   = alloc((size_t)BB * HP * 2);
    size_t o_qbk1   = alloc(BB * 4);
    size_t o_sc1    = alloc((size_t)BB * TT * 4);
    size_t o_aw1    = alloc((size_t)BB * TT * 4);
    size_t o_q2     = alloc((size_t)BB * EE * 2);
    size_t o_qk2    = alloc((size_t)BB * EE * 2);
    size_t o_u2     = alloc((size_t)BB * EE * 2);
    size_t o_vc2    = alloc((size_t)BB * EE * 2);
    size_t o_ctx2   = alloc((size_t)BB * EE * 2);
    size_t o_qbk2   = alloc(BB * 4);
    size_t o_sc2    = alloc((size_t)BB * TT * 4);
    size_t o_aw2    = alloc((size_t)BB * TT * 4);
    size_t o_h1f    = alloc((size_t)BB * HP * 2);
    size_t o_h2f    = alloc((size_t)BB * EE * 2);

    if (ws_size < cur) {
        fail_k<<<3, 256, 0, stream>>>(out);
        return;
    }

    // ---------- prep ----------
    ln_x_k<<<BB * TT, 256, 0, stream>>>(x, in_g, in_b, US(o_xnhi), US(o_xnlo));
    castsplit_k<<<(HP * EE + 255) / 256, 256, 0, stream>>>(w_ih1, HH, EE, US(o_wih1hi), US(o_wih1lo), HP, EE);
    castsplit_k<<<(HP * HP + 255) / 256, 256, 0, stream>>>(w_hh1, HH, HH, US(o_whh1hi), US(o_whh1lo), HP, HP);
    castpad_k<<<(EE * HP + 255) / 256, 256, 0, stream>>>(w_ih2, EE, HH, US(o_wih2), EE, HP);
    castpad_k<<<(EE * EE + 255) / 256, 256, 0, stream>>>(w_hh2, EE, EE, US(o_whh2), EE, EE);
    biascomb_k<<<(HP + 255) / 256, 256, 0, stream>>>(b_ih1, b_hh1, FP(o_b1c), HH, HP);
    biascomb_k<<<(EE + 255) / 256, 256, 0, stream>>>(b_ih2, b_hh2, FP(o_b2c), EE, EE);
    padcopy_k<<<(HP + 255) / 256, 256, 0, stream>>>(ln1_g, FP(o_gpad), HH, HP);
    padcopy_k<<<(HP + 255) / 256, 256, 0, stream>>>(ln1_b, FP(o_bepad), HH, HP);
    castpad_k<<<(HP * HP + 255) / 256, 256, 0, stream>>>(m1_wqkv, HH, HH, US(o_wq1), HP, HP);
    castpad_k<<<(HP * HP + 255) / 256, 256, 0, stream>>>(m1_wqkv + (size_t)2 * HH * HH, HH, HH, US(o_wv1), HP, HP);
    castpad_k<<<(HP * HP + 255) / 256, 256, 0, stream>>>(m1_wo, HH, HH, US(o_wo1), HP, HP);
    transcast_k<<<dim3(HP / 32, HP / 32), 256, 0, stream>>>(m1_wqkv + (size_t)HH * HH, HH, HH, US(o_wk1T), HP, HP);
    castpad_k<<<(EE * EE + 255) / 256, 256, 0, stream>>>(m2_wqkv, EE, EE, US(o_wq2), EE, EE);
    castpad_k<<<(EE * EE + 255) / 256, 256, 0, stream>>>(m2_wqkv + (size_t)2 * EE * EE, EE, EE, US(o_wv2), EE, EE);
    castpad_k<<<(EE * EE + 255) / 256, 256, 0, stream>>>(m2_wo, EE, EE, US(o_wo2), EE, EE);
    transcast_k<<<dim3(EE / 32, EE / 32), 256, 0, stream>>>(m2_wqkv + (size_t)EE * EE, EE, EE, US(o_wk2T), EE, EE);
    hipMemsetAsync(US(o_h2hi), 0, (size_t)BB * EE * 2, stream);
    hipMemsetAsync(US(o_h2lo), 0, (size_t)BB * EE * 2, stream);
    hipMemsetAsync(ws + o_sync, 0, 64 * 128 + 256, stream);

    // ---------- persistent RNN loop ----------
    PP pp;
    pp.xnhi = US(o_xnhi); pp.xnlo = US(o_xnlo);
    pp.wih1hi = US(o_wih1hi); pp.wih1lo = US(o_wih1lo);
    pp.whh1hi = US(o_whh1hi); pp.whh1lo = US(o_whh1lo);
    pp.wih2 = US(o_wih2); pp.whh2 = US(o_whh2);
    pp.b1c = FP(o_b1c); pp.b2c = FP(o_b2c);
    pp.gpad = FP(o_gpad); pp.bepad = FP(o_bepad);
    pp.h1nhi = US(o_h1nhi); pp.h1nlo = US(o_h1nlo);
    pp.h2hi = US(o_h2hi); pp.h2lo = US(o_h2lo);
    pp.part1 = FP(o_part1); pp.part2 = FP(o_part2);
    pp.h1s = US(o_h1s); pp.h2s = US(o_h2s);
    pp.grp = (unsigned int*)(ws + o_sync);
    pp.epoch = (unsigned int*)(ws + o_sync + 64 * 128);
    persist_k<<<NBLK, NTHR, 0, stream>>>(pp);

    const unsigned short* h1last = US(o_h1s) + (size_t)(TT - 1) * BB * HP;
    const unsigned short* h2last = US(o_h2s) + (size_t)(TT - 1) * BB * EE;
    const float sc_scale1 = 1.0f / sqrtf((float)HH);
    const float sc_scale2 = 1.0f / sqrtf((float)EE);

    // ---------- MHA1 (only last-row context needed) ----------
    gemm32_k<<<dim3(HP / 64, 7), 256, 0, stream>>>(h1last, US(o_wq1), FP(o_part1), HP, HP, 14, 0);
    epi_k<<<BB * HP / 256, 256, 0, stream>>>(FP(o_part1), 7, HP, HH, m1_bqkv, 0, US(o_q1));
    gemm32_k<<<dim3(HP / 64, 7), 256, 0, stream>>>(US(o_q1), US(o_wk1T), FP(o_part1), HP, HP, 14, 0);
    epi_k<<<BB * HP / 256, 256, 0, stream>>>(FP(o_part1), 7, HP, HH, nullptr, 0, US(o_qk1));
    qbk_k<<<BB, 256, 0, stream>>>(US(o_q1), HP, HH, m1_bqkv + HH, FP(o_qbk1));
    scores_k<<<BB * TT / 4, 256, 0, stream>>>(US(o_h1s), US(o_qk1), FP(o_qbk1), FP(o_sc1), HP, sc_scale1);
    softmax_k<<<BB, 256, 0, stream>>>(FP(o_sc1), FP(o_aw1));
    attnsum_k<<<BB * HP / 256, 256, 0, stream>>>(US(o_h1s), FP(o_aw1), US(o_u1), HP);
    gemm32_k<<<dim3(HP / 64, 7), 256, 0, stream>>>(US(o_u1), US(o_wv1), FP(o_part1), HP, HP, 14, 0);
    epi_k<<<BB * HP / 256, 256, 0, stream>>>(FP(o_part1), 7, HP, HH, m1_bqkv + 2 * HH, 0, US(o_vc1));
    gemm32_k<<<dim3(HP / 64, 7), 256, 0, stream>>>(US(o_vc1), US(o_wo1), FP(o_part1), HP, HP, 14, 0);
    epi_k<<<BB * HP / 256, 256, 0, stream>>>(FP(o_part1), 7, HP, HH, m1_bo, 0, US(o_ctx1));

    // ---------- MHA2 ----------
    gemm32_k<<<dim3(EE / 64, 3), 256, 0, stream>>>(h2last, US(o_wq2), FP(o_part2), EE, EE, 8, 0);
    epi_k<<<BB * EE / 256, 256, 0, stream>>>(FP(o_part2), 3, EE, EE, m2_bqkv, 0, US(o_q2));
    gemm32_k<<<dim3(EE / 64, 3), 256, 0, stream>>>(US(o_q2), US(o_wk2T), FP(o_part2), EE, EE, 8, 0);
    epi_k<<<BB * EE / 256, 256, 0, stream>>>(FP(o_part2), 3, EE, EE, nullptr, 0, US(o_qk2));
    qbk_k<<<BB, 256, 0, stream>>>(US(o_q2), EE, EE, m2_bqkv + EE, FP(o_qbk2));
    scores_k<<<BB * TT / 4, 256, 0, stream>>>(US(o_h2s), US(o_qk2), FP(o_qbk2), FP(o_sc2), EE, sc_scale2);
    softmax_k<<<BB, 256, 0, stream>>>(FP(o_sc2), FP(o_aw2));
    attnsum_k<<<BB * EE / 256, 256, 0, stream>>>(US(o_h2s), FP(o_aw2), US(o_u2), EE);
    gemm32_k<<<dim3(EE / 64, 3), 256, 0, stream>>>(US(o_u2), US(o_wv2), FP(o_part2), EE, EE, 8, 0);
    epi_k<<<BB * EE / 256, 256, 0, stream>>>(FP(o_part2), 3, EE, EE, m2_bqkv + 2 * EE, 0, US(o_vc2));
    gemm32_k<<<dim3(EE / 64, 3), 256, 0, stream>>>(US(o_vc2), US(o_wo2), FP(o_part2), EE, EE, 8, 0);
    epi_k<<<BB * EE / 256, 256, 0, stream>>>(FP(o_part2), 3, EE, EE, m2_bo, 0, US(o_ctx2));

    // ---------- final cells ----------
    const unsigned short* xnlast = US(o_xnhi) + (size_t)(TT - 1) * BB * EE;
    gemm32_k<<<dim3(HP / 64, 1), 256, 0, stream>>>(xnlast, US(o_wih1hi), FP(o_part1), EE, HP, EE / 32, 0);
    gemm32_k<<<dim3(HP / 64, 7), 256, 0, stream>>>(US(o_ctx1), US(o_whh1hi), FP(o_part1), HP, HP, 14, 1);
    epi_k<<<BB * HP / 256, 256, 0, stream>>>(FP(o_part1), 8, HP, HH, FP(o_b1c), 1, US(o_h1f));
    gemm32_k<<<dim3(EE / 64, 7), 256, 0, stream>>>(US(o_h1f), US(o_wih2), FP(o_part2), HP, EE, 14, 0);
    gemm32_k<<<dim3(EE / 64, 1), 256, 0, stream>>>(US(o_ctx2), US(o_whh2), FP(o_part2), EE, EE, EE / 32, 7);
    epi_k<<<BB * EE / 256, 256, 0, stream>>>(FP(o_part2), 8, EE, EE, FP(o_b2c), 1, US(o_h2f));
    cls_k<<<BB, 256, 0, stream>>>(US(o_h2f), w_cls, b_cls, out);
}

// Round 6
// 28636.343 us; speedup vs baseline: 7.1896x; 1.0659x over previous
//
#include <hip/hip_runtime.h>
#include <cstdint>
#include <cmath>

// ---------------- constants ----------------
#define BB 32
#define TT 512
#define EE 768
#define HH 3132
#define HP 3136   // H padded to mult of 64
#define OO 19

#define NBLK 320
#define NTHR 256
#define PITCH 472   // LDS row pitch (944B, 16B-aligned) — round-4 proven

// phase-A task map: blk 0..174 = T1 (rt=blk/7, ks=blk%7, 128x448 tiles)
//                   blk 175..258 = T2 (Wih2@h1, 64x448)
//                   blk 259..270 = T3 (Whh2@h2, 64xK768)
// phase-B: blk 0..31 = U1 (h1 finish), blk 32..63 = U2 (h2 finish)
#define T1_END 175
#define T2_END 259
#define T3_END 271

// time-permutation for state rings (kills cross-step address adjacency)
#define PT(t) (((t) * 331) & 511)

typedef __attribute__((ext_vector_type(8))) short s8v;
typedef __attribute__((ext_vector_type(4))) float f4v;
typedef __attribute__((ext_vector_type(8))) unsigned short u16x8;

__device__ __forceinline__ unsigned short f2bf(float f) {
    uint32_t u = __float_as_uint(f);
    uint32_t r = u + 0x7FFFu + ((u >> 16) & 1u);
    return (unsigned short)(r >> 16);
}
__device__ __forceinline__ float bf2f(unsigned short h) {
    return __uint_as_float(((uint32_t)h) << 16);
}

#define MFMA(a, b, c) __builtin_amdgcn_mfma_f32_16x16x32_bf16((a), (b), (c), 0, 0, 0)

// ---- sc1 primitives: LLC-coherent, no cache invalidation ----
__device__ __forceinline__ f4v ld4_sc(const void* p) {
    f4v v;
    asm volatile("global_load_dwordx4 %0, %1, off sc0 sc1" : "=v"(v) : "v"(p) : "memory");
    return v;   // valid only after WAITV()
}
#define WAITV() do { asm volatile("s_waitcnt vmcnt(0)" ::: "memory"); \
                     __builtin_amdgcn_sched_barrier(0); } while (0)
__device__ __forceinline__ void st_sc(float* p, float v) {
    __hip_atomic_store(p, v, __ATOMIC_RELAXED, __HIP_MEMORY_SCOPE_AGENT);
}
__device__ __forceinline__ void st16_sc(void* p, u16x8 v) {
    asm volatile("global_store_dwordx4 %0, %1, off sc0 sc1" :: "v"(p), "v"(v) : "memory");
}
__device__ __forceinline__ void st8_sc(void* p, uint2 v) {
    asm volatile("global_store_dwordx2 %0, %1, off sc0 sc1" :: "v"(p), "v"(v) : "memory");
}

// ---------------- persistent-kernel params ----------------
struct PP {
    const unsigned short *xw1hi, *xw1lo;          // precomputed Wih1@xn, bf16 pair (normal reads)
    const unsigned short *whh1hi, *whh1lo, *wih2, *whh2;
    const float *b1c, *b2c, *gpad, *bepad;
    unsigned short *h1hist, *h2hist;              // full-T rings (hi): sc1-written, NORMAL-read
    unsigned short *h1nlo, *h2lo;                 // lo single buffers: sc1 both ways
    float *part1, *part2;                         // sc1 both ways
    unsigned int *grp;                            // 64 groups, 128B stride
    unsigned int *epoch;
};

// ---------------- relaxed hierarchical grid barrier ----------------
__device__ __forceinline__ void gbar(const PP& p, unsigned int k) {
    __syncthreads();
    asm volatile("s_waitcnt vmcnt(0)" ::: "memory");   // all stores (incl. sc1) ACKed at LLC
    if (threadIdx.x == 0)
        __hip_atomic_fetch_add(&p.grp[(blockIdx.x & 63) * 32], 1u,
                               __ATOMIC_RELAXED, __HIP_MEMORY_SCOPE_AGENT);
    if (blockIdx.x == 0) {
        if (threadIdx.x < 64) {
            unsigned int tgt = 5u * k;          // NBLK=320 = 64 groups x 5
            long g = 0;
            while (__hip_atomic_load(&p.grp[threadIdx.x * 32], __ATOMIC_RELAXED,
                                     __HIP_MEMORY_SCOPE_AGENT) < tgt) {
                __builtin_amdgcn_s_sleep(2);
                if (++g > (1L << 16)) break;
            }
        }
        __syncthreads();
        if (threadIdx.x == 0)
            __hip_atomic_store(p.epoch, k, __ATOMIC_RELAXED, __HIP_MEMORY_SCOPE_AGENT);
    } else {
        if (threadIdx.x == 0) {
            long g = 0;
            while (__hip_atomic_load(p.epoch, __ATOMIC_RELAXED,
                                     __HIP_MEMORY_SCOPE_AGENT) < k) {
                __builtin_amdgcn_s_sleep(2);
                if (++g > (1L << 16)) break;
            }
        }
    }
    __syncthreads();
    asm volatile("" ::: "memory");   // block compiler hoisting of next-phase loads above the spin
}

__global__ __launch_bounds__(NTHR, 2) void persist_k(PP p) {
    __shared__ unsigned short Ah[32][PITCH];
    __shared__ unsigned short Al[32][PITCH];
    __shared__ float redS[4], redQ[4];
    const int blk = blockIdx.x, tid = threadIdx.x;
    const int wid = tid >> 6, lane = tid & 63;
    const int r = lane & 15, kg = lane >> 4;
    unsigned int bar = 0;

    for (int t = 0; t <= TT; ++t) {
        // ===================== PHASE A =====================
        if (blk < T1_END) {
            // T1: part1[ks] = Whh1 @ h1[t-1]  (split precision; hi via ring NORMAL, lo via sc1)
            if (t >= 1 && t <= TT - 1) {
                int rt = blk / 7, ks = blk % 7;
                int n0 = rt * 128;
                int nrows = (rt == 24) ? 64 : 128;
                {   // stage A (32 x 448, hi + lo)
                    const unsigned short* srchi = p.h1hist + (size_t)PT(t - 1) * BB * HP + ks * 448;
                    const unsigned short* srclo = p.h1nlo + ks * 448;
                    uint4 hv[7]; f4v lv[7];
                    #pragma unroll
                    for (int i = 0; i < 7; ++i) {
                        int g = tid + i * 256, row = g / 56, c16 = g % 56;
                        hv[i] = *(const uint4*)(srchi + (size_t)row * HP + c16 * 8);   // normal
                        lv[i] = ld4_sc(srclo + (size_t)row * HP + c16 * 8);            // sc1
                    }
                    WAITV();
                    #pragma unroll
                    for (int i = 0; i < 7; ++i) {
                        int g = tid + i * 256, row = g / 56, c16 = g % 56;
                        *(uint4*)&Ah[row][c16 * 8] = hv[i];
                        *(f4v*)&Al[row][c16 * 8] = lv[i];
                    }
                }
                __syncthreads();
                int rpw = nrows >> 2;             // rows per wave: 32 or 16
                int ntw = rpw >> 4;               // n-tiles per wave: 2 or 1
                int wn0 = n0 + wid * rpw;
                auto t1_tile = [&](const unsigned short* Whr, const unsigned short* Wlr, float* pp1) {
                    f4v a0 = {0.f,0.f,0.f,0.f}, a1 = {0.f,0.f,0.f,0.f};
                    #pragma unroll
                    for (int kb = 0; kb < 14; ++kb) {
                        s8v bh  = *(const s8v*)(Whr + kb * 32);
                        s8v bl  = *(const s8v*)(Wlr + kb * 32);
                        s8v xh0 = *(const s8v*)&Ah[r][kg * 8 + kb * 32];
                        s8v xh1 = *(const s8v*)&Ah[r + 16][kg * 8 + kb * 32];
                        s8v xl0 = *(const s8v*)&Al[r][kg * 8 + kb * 32];
                        s8v xl1 = *(const s8v*)&Al[r + 16][kg * 8 + kb * 32];
                        a0 = MFMA(xh0, bh, a0); a1 = MFMA(xh1, bh, a1);
                        a0 = MFMA(xl0, bh, a0); a1 = MFMA(xl1, bh, a1);
                        a0 = MFMA(xh0, bl, a0); a1 = MFMA(xh1, bl, a1);
                    }
                    #pragma unroll
                    for (int q = 0; q < 4; ++q) {
                        st_sc(pp1 + (size_t)(kg * 4 + q) * HP,      a0[q]);
                        st_sc(pp1 + (size_t)(kg * 4 + q + 16) * HP, a1[q]);
                    }
                };
                const unsigned short* Wh0 = p.whh1hi + (size_t)(wn0 + r) * HP + ks * 448 + kg * 8;
                const unsigned short* Wl0 = p.whh1lo + (size_t)(wn0 + r) * HP + ks * 448 + kg * 8;
                float* pb = p.part1 + (size_t)ks * BB * HP + wn0 + r;
                t1_tile(Wh0, Wl0, pb);
                if (ntw == 2) t1_tile(Wh0 + (size_t)16 * HP, Wl0 + (size_t)16 * HP, pb + 16);
            }
        } else if (blk < T2_END) {
            // T2: part2[ks] = Wih2 @ h1[t-1]  (hi only, ring NORMAL)
            if (t >= 1) {
                int id = blk - T1_END, nt = id / 7, ks = id % 7;
                {
                    const unsigned short* srchi = p.h1hist + (size_t)PT(t - 1) * BB * HP + ks * 448;
                    uint4 hv[7];
                    #pragma unroll
                    for (int i = 0; i < 7; ++i) {
                        int g = tid + i * 256, row = g / 56, c16 = g % 56;
                        hv[i] = *(const uint4*)(srchi + (size_t)row * HP + c16 * 8);
                    }
                    #pragma unroll
                    for (int i = 0; i < 7; ++i) {
                        int g = tid + i * 256, row = g / 56, c16 = g % 56;
                        *(uint4*)&Ah[row][c16 * 8] = hv[i];
                    }
                }
                __syncthreads();
                int wn0 = nt * 64 + wid * 16;
                const unsigned short* Whr = p.wih2 + (size_t)(wn0 + r) * HP + ks * 448 + kg * 8;
                f4v a0 = {0.f,0.f,0.f,0.f}, a1 = {0.f,0.f,0.f,0.f};
                #pragma unroll
                for (int kb = 0; kb < 14; ++kb) {
                    s8v bh  = *(const s8v*)(Whr + kb * 32);
                    s8v xh0 = *(const s8v*)&Ah[r][kg * 8 + kb * 32];
                    s8v xh1 = *(const s8v*)&Ah[r + 16][kg * 8 + kb * 32];
                    a0 = MFMA(xh0, bh, a0); a1 = MFMA(xh1, bh, a1);
                }
                float* pp2 = p.part2 + (size_t)ks * BB * EE + wn0 + r;
                #pragma unroll
                for (int q = 0; q < 4; ++q) {
                    st_sc(pp2 + (size_t)(kg * 4 + q) * EE,      a0[q]);
                    st_sc(pp2 + (size_t)(kg * 4 + q + 16) * EE, a1[q]);
                }
            }
        } else if (blk < T3_END) {
            // T3: part2[7] = Whh2 @ h2[t-2]  (hi via ring NORMAL, lo via sc1)
            if (t >= 2) {
                int nt = blk - T2_END;
                int wn0 = nt * 64 + wid * 16;
                const unsigned short* Whr = p.whh2 + (size_t)(wn0 + r) * EE + kg * 8;
                const unsigned short* Hh = p.h2hist + (size_t)PT(t - 2) * BB * EE;
                const unsigned short* Hl = p.h2lo;
                f4v a0 = {0.f,0.f,0.f,0.f}, a1 = {0.f,0.f,0.f,0.f};
                #pragma unroll
                for (int c = 0; c < 4; ++c) {
                    uint4 v0h[6], v1h[6]; f4v v0l[6], v1l[6];
                    #pragma unroll
                    for (int u = 0; u < 6; ++u) {
                        int kb = c * 6 + u;
                        v0h[u] = *(const uint4*)(Hh + (size_t)r * EE + kg * 8 + kb * 32);
                        v1h[u] = *(const uint4*)(Hh + (size_t)(r + 16) * EE + kg * 8 + kb * 32);
                        v0l[u] = ld4_sc(Hl + (size_t)r * EE + kg * 8 + kb * 32);
                        v1l[u] = ld4_sc(Hl + (size_t)(r + 16) * EE + kg * 8 + kb * 32);
                    }
                    WAITV();
                    #pragma unroll
                    for (int u = 0; u < 6; ++u) {
                        int kb = c * 6 + u;
                        s8v bh = *(const s8v*)(Whr + kb * 32);
                        a0 = MFMA(__builtin_bit_cast(s8v, v0h[u]), bh, a0);
                        a0 = MFMA(__builtin_bit_cast(s8v, v0l[u]), bh, a0);
                        a1 = MFMA(__builtin_bit_cast(s8v, v1h[u]), bh, a1);
                        a1 = MFMA(__builtin_bit_cast(s8v, v1l[u]), bh, a1);
                    }
                }
                float* pp2 = p.part2 + (size_t)7 * BB * EE + wn0 + r;
                #pragma unroll
                for (int q = 0; q < 4; ++q) {
                    st_sc(pp2 + (size_t)(kg * 4 + q) * EE,      a0[q]);
                    st_sc(pp2 + (size_t)(kg * 4 + q + 16) * EE, a1[q]);
                }
            }
        }
        gbar(p, ++bar);

        // ===================== PHASE B =====================
        if (blk < 32) {
            // U1: h1[t] = LN(tanh(sum part1 + xw1[t] + b)); write ring hi (sc1) + lo buf (sc1)
            if (t <= TT - 1) {
                const int b = blk;
                const int nb = tid * 16;
                const bool act = (tid < 196);
                float acc[16];
                float s = 0.f, s2 = 0.f;
                if (act) {
                    #pragma unroll
                    for (int k4 = 0; k4 < 4; ++k4) {
                        f4v bb = *(const f4v*)(p.b1c + nb + k4 * 4);
                        #pragma unroll
                        for (int e = 0; e < 4; ++e) acc[k4 * 4 + e] = bb[e];
                    }
                    const u16x8* xh = (const u16x8*)(p.xw1hi + ((size_t)t * BB + b) * HP + nb);
                    const u16x8* xl = (const u16x8*)(p.xw1lo + ((size_t)t * BB + b) * HP + nb);
                    u16x8 h0v = xh[0], h1v = xh[1], l0v = xl[0], l1v = xl[1];
                    #pragma unroll
                    for (int j = 0; j < 8; ++j) acc[j]     += bf2f(h0v[j]) + bf2f(l0v[j]);
                    #pragma unroll
                    for (int j = 0; j < 8; ++j) acc[8 + j] += bf2f(h1v[j]) + bf2f(l1v[j]);
                    if (t > 0) {
                        {   // slots 0..3
                            f4v tmp[16];
                            #pragma unroll
                            for (int sl = 0; sl < 4; ++sl) {
                                const float* base = p.part1 + ((size_t)sl * BB + b) * HP + nb;
                                #pragma unroll
                                for (int k4 = 0; k4 < 4; ++k4) tmp[sl * 4 + k4] = ld4_sc(base + k4 * 4);
                            }
                            WAITV();
                            #pragma unroll
                            for (int sl = 0; sl < 4; ++sl)
                                #pragma unroll
                                for (int k4 = 0; k4 < 4; ++k4)
                                    #pragma unroll
                                    for (int e = 0; e < 4; ++e) acc[k4 * 4 + e] += tmp[sl * 4 + k4][e];
                        }
                        {   // slots 4..6
                            f4v tmp[12];
                            #pragma unroll
                            for (int sl = 0; sl < 3; ++sl) {
                                const float* base = p.part1 + ((size_t)(sl + 4) * BB + b) * HP + nb;
                                #pragma unroll
                                for (int k4 = 0; k4 < 4; ++k4) tmp[sl * 4 + k4] = ld4_sc(base + k4 * 4);
                            }
                            WAITV();
                            #pragma unroll
                            for (int sl = 0; sl < 3; ++sl)
                                #pragma unroll
                                for (int k4 = 0; k4 < 4; ++k4)
                                    #pragma unroll
                                    for (int e = 0; e < 4; ++e) acc[k4 * 4 + e] += tmp[sl * 4 + k4][e];
                        }
                    }
                    #pragma unroll
                    for (int j = 0; j < 16; ++j) {
                        if (nb + j < HH) {
                            float v = tanhf(acc[j]);
                            acc[j] = v; s += v; s2 += v * v;
                        } else acc[j] = 0.f;
                    }
                }
                for (int o = 32; o; o >>= 1) { s += __shfl_xor(s, o); s2 += __shfl_xor(s2, o); }
                if (lane == 0) { redS[wid] = s; redQ[wid] = s2; }
                __syncthreads();
                float S  = redS[0] + redS[1] + redS[2] + redS[3];
                float S2 = redQ[0] + redQ[1] + redQ[2] + redQ[3];
                float mm = S / (float)HH;
                float inv = rsqrtf(S2 / (float)HH - mm * mm + 1e-5f);
                __syncthreads();
                if (act) {
                    u16x8 ho0, ho1, lo0, lo1;
                    #pragma unroll
                    for (int k4 = 0; k4 < 4; ++k4) {
                        f4v gv = *(const f4v*)(p.gpad + nb + k4 * 4);
                        f4v bv = *(const f4v*)(p.bepad + nb + k4 * 4);
                        #pragma unroll
                        for (int e = 0; e < 4; ++e) {
                            int j = k4 * 4 + e, n = nb + j;
                            float o = (n < HH) ? (acc[j] - mm) * inv * gv[e] + bv[e] : 0.f;
                            unsigned short hb = f2bf(o);
                            unsigned short lb = f2bf(o - bf2f(hb));
                            if (j < 8) { ho0[j] = hb; lo0[j] = lb; }
                            else       { ho1[j - 8] = hb; lo1[j - 8] = lb; }
                        }
                    }
                    unsigned short* dh = p.h1hist + ((size_t)PT(t) * BB + b) * HP + nb;
                    unsigned short* dl = p.h1nlo + (size_t)b * HP + nb;
                    st16_sc(dh, ho0); st16_sc(dh + 8, ho1);
                    st16_sc(dl, lo0); st16_sc(dl + 8, lo1);
                }
            }
        } else if (blk < 64) {
            // U2: h2[t-1] = tanh(sum part2 + b); write ring hi (sc1) + lo buf (sc1)
            if (t >= 1) {
                const int b = blk - 32;
                if (tid < 192) {
                    const int nb = tid * 4;
                    f4v a4 = *(const f4v*)(p.b2c + nb);
                    f4v tp[8];
                    #pragma unroll
                    for (int sl = 0; sl < 8; ++sl)
                        tp[sl] = ld4_sc(p.part2 + ((size_t)sl * BB + b) * EE + nb);
                    WAITV();
                    #pragma unroll
                    for (int sl = 0; sl < 8; ++sl) {
                        float w = (t == 1 && sl == 7) ? 0.f : 1.f;   // h2[-1] = 0
                        #pragma unroll
                        for (int e = 0; e < 4; ++e) a4[e] += w * tp[sl][e];
                    }
                    unsigned short hb4[4], lb4[4];
                    #pragma unroll
                    for (int e = 0; e < 4; ++e) {
                        float v = tanhf(a4[e]);
                        hb4[e] = f2bf(v); lb4[e] = f2bf(v - bf2f(hb4[e]));
                    }
                    uint2 hp_, lp_;
                    hp_.x = (unsigned)hb4[0] | ((unsigned)hb4[1] << 16);
                    hp_.y = (unsigned)hb4[2] | ((unsigned)hb4[3] << 16);
                    lp_.x = (unsigned)lb4[0] | ((unsigned)lb4[1] << 16);
                    lp_.y = (unsigned)lb4[2] | ((unsigned)lb4[3] << 16);
                    st8_sc(p.h2hist + ((size_t)PT(t - 1) * BB + b) * EE + nb, hp_);
                    st8_sc(p.h2lo + (size_t)b * EE + nb, lp_);
                }
            }
        }
        gbar(p, ++bar);
    }
}

// ---------------- prep kernels ----------------
__global__ void ln_x_k(const float* __restrict__ x, const float* __restrict__ g,
                       const float* __restrict__ be, unsigned short* __restrict__ xnhi,
                       unsigned short* __restrict__ xnlo) {
    int bt = blockIdx.x;
    int b = bt >> 9, t = bt & 511;
    const float* row = x + ((size_t)b * TT + t) * EE;
    int tid = threadIdx.x;
    float v0 = row[tid], v1 = row[tid + 256], v2 = row[tid + 512];
    float s = v0 + v1 + v2, s2 = v0 * v0 + v1 * v1 + v2 * v2;
    for (int o = 32; o; o >>= 1) { s += __shfl_xor(s, o); s2 += __shfl_xor(s2, o); }
    __shared__ float r1[4], r2[4];
    int wid = tid >> 6, lane = tid & 63;
    if (lane == 0) { r1[wid] = s; r2[wid] = s2; }
    __syncthreads();
    s = r1[0] + r1[1] + r1[2] + r1[3];
    s2 = r2[0] + r2[1] + r2[2] + r2[3];
    float m = s / (float)EE, var = s2 / (float)EE - m * m;
    float inv = rsqrtf(var + 1e-5f);
    size_t ro = ((size_t)t * BB + b) * EE;
    float vals[3] = {v0, v1, v2};
#pragma unroll
    for (int i = 0; i < 3; i++) {
        int e = tid + i * 256;
        float o = (vals[i] - m) * inv * g[e] + be[e];
        unsigned short hb = f2bf(o);
        xnhi[ro + e] = hb;
        xnlo[ro + e] = f2bf(o - bf2f(hb));
    }
}

__global__ void castpad_k(const float* __restrict__ in, int N, int K,
                          unsigned short* __restrict__ out, int Np, int Kp) {
    size_t gid = (size_t)blockIdx.x * 256 + threadIdx.x;
    if (gid >= (size_t)Np * Kp) return;
    int n = (int)(gid / Kp), k = (int)(gid % Kp);
    out[gid] = (n < N && k < K) ? f2bf(in[(size_t)n * K + k]) : (unsigned short)0;
}

__global__ void castsplit_k(const float* __restrict__ in, int N, int K,
                            unsigned short* __restrict__ hi, unsigned short* __restrict__ lo,
                            int Np, int Kp) {
    size_t gid = (size_t)blockIdx.x * 256 + threadIdx.x;
    if (gid >= (size_t)Np * Kp) return;
    int n = (int)(gid / Kp), k = (int)(gid % Kp);
    float v = (n < N && k < K) ? in[(size_t)n * K + k] : 0.0f;
    unsigned short hb = f2bf(v);
    hi[gid] = hb;
    lo[gid] = f2bf(v - bf2f(hb));
}

__global__ void transcast_k(const float* __restrict__ in, int R, int C,
                            unsigned short* __restrict__ out, int Rp, int Cp) {
    __shared__ float tile[32][33];
    int c0 = blockIdx.x * 32, r0 = blockIdx.y * 32;
    int tx = threadIdx.x & 31, ty = threadIdx.x >> 5;
    for (int i = 0; i < 4; i++) {
        int r = r0 + ty + i * 8, c = c0 + tx;
        tile[ty + i * 8][tx] = (r < R && c < C) ? in[(size_t)r * C + c] : 0.0f;
    }
    __syncthreads();
    for (int i = 0; i < 4; i++) {
        int c = c0 + ty + i * 8, r = r0 + tx;
        if (c < Cp && r < Rp) out[(size_t)c * Rp + r] = f2bf(tile[tx][ty + i * 8]);
    }
}

__global__ void biascomb_k(const float* a, const float* b, float* o, int realN, int Np) {
    int gid = blockIdx.x * 256 + threadIdx.x;
    if (gid >= Np) return;
    o[gid] = (gid < realN) ? a[gid] + b[gid] : 0.0f;
}

__global__ void padcopy_k(const float* in, float* out, int realN, int Np) {
    int gid = blockIdx.x * 256 + threadIdx.x;
    if (gid >= Np) return;
    out[gid] = (gid < realN) ? in[gid] : 0.0f;
}

// big split GEMM: xw1 = xn @ wih1^T, out bf16 hi/lo.  grid (TB/32, HP/64)
__global__ __launch_bounds__(256) void gemmbig_k(const unsigned short* __restrict__ Ahi,
                                                 const unsigned short* __restrict__ Alo,
                                                 const unsigned short* __restrict__ Whi,
                                                 const unsigned short* __restrict__ Wlo,
                                                 unsigned short* __restrict__ outhi,
                                                 unsigned short* __restrict__ outlo,
                                                 int Kld, int Np, int ksteps) {
    int m0 = blockIdx.x * 32;
    int n0 = blockIdx.y * 64;
    int wid = threadIdx.x >> 6, lane = threadIdx.x & 63;
    int r = lane & 15, kg = lane >> 4;
    size_t woff = (size_t)(n0 + wid * 16 + r) * Kld + kg * 8;
    const unsigned short* Whr = Whi + woff;
    const unsigned short* Wlr = Wlo + woff;
    size_t aoff = (size_t)(m0 + r) * Kld + kg * 8;
    const unsigned short* Ah0 = Ahi + aoff;
    const unsigned short* Ah1 = Ah0 + (size_t)16 * Kld;
    const unsigned short* Al0 = Alo + aoff;
    const unsigned short* Al1 = Al0 + (size_t)16 * Kld;
    f4v acc0 = {0.f, 0.f, 0.f, 0.f}, acc1 = {0.f, 0.f, 0.f, 0.f};
#pragma unroll 4
    for (int s = 0; s < ksteps; s++) {
        s8v bh  = *(const s8v*)(Whr + s * 32);
        s8v bl  = *(const s8v*)(Wlr + s * 32);
        s8v a0h = *(const s8v*)(Ah0 + s * 32);
        s8v a1h = *(const s8v*)(Ah1 + s * 32);
        s8v a0l = *(const s8v*)(Al0 + s * 32);
        s8v a1l = *(const s8v*)(Al1 + s * 32);
        acc0 = MFMA(a0h, bh, acc0); acc1 = MFMA(a1h, bh, acc1);
        acc0 = MFMA(a0l, bh, acc0); acc1 = MFMA(a1l, bh, acc1);
        acc0 = MFMA(a0h, bl, acc0); acc1 = MFMA(a1h, bl, acc1);
    }
    int ncol = n0 + wid * 16 + r;
#pragma unroll
    for (int q = 0; q < 4; q++) {
        int m = kg * 4 + q;
        float v0 = acc0[q], v1 = acc1[q];
        unsigned short h0 = f2bf(v0), h1 = f2bf(v1);
        outhi[(size_t)(m0 + m) * Np + ncol]      = h0;
        outlo[(size_t)(m0 + m) * Np + ncol]      = f2bf(v0 - bf2f(h0));
        outhi[(size_t)(m0 + m + 16) * Np + ncol] = h1;
        outlo[(size_t)(m0 + m + 16) * Np + ncol] = f2bf(v1 - bf2f(h1));
    }
}

// ---------------- tail kernels ----------------
__global__ __launch_bounds__(256) void gemm32_k(const unsigned short* __restrict__ A,
                                                const unsigned short* __restrict__ W,
                                                float* __restrict__ part,
                                                int Kld, int Np, int ksteps, int slot_base) {
    int n0 = blockIdx.x * 64;
    int kb = blockIdx.y;
    int k0 = kb * ksteps * 32;
    int wid = threadIdx.x >> 6, lane = threadIdx.x & 63;
    int r = lane & 15, kg = lane >> 4;
    const unsigned short* Wrow = W + (size_t)(n0 + wid * 16 + r) * Kld + k0 + kg * 8;
    const unsigned short* Ar0 = A + (size_t)r * Kld + k0 + kg * 8;
    const unsigned short* Ar1 = Ar0 + (size_t)16 * Kld;
    f4v acc0 = {0.f, 0.f, 0.f, 0.f}, acc1 = {0.f, 0.f, 0.f, 0.f};
#pragma unroll
    for (int s = 0; s < ksteps; s++) {
        s8v bf = *(const s8v*)(Wrow + s * 32);
        s8v a0 = *(const s8v*)(Ar0 + s * 32);
        s8v a1 = *(const s8v*)(Ar1 + s * 32);
        acc0 = MFMA(a0, bf, acc0);
        acc1 = MFMA(a1, bf, acc1);
    }
    int ncol = n0 + wid * 16 + r;
    float* p = part + (size_t)(slot_base + kb) * 32 * Np + ncol;
#pragma unroll
    for (int q = 0; q < 4; q++) {
        int m = kg * 4 + q;
        p[(size_t)m * Np]        = acc0[q];
        p[(size_t)(m + 16) * Np] = acc1[q];
    }
}

__global__ void epi_k(const float* __restrict__ part, int nslots, int Np, int realN,
                      const float* __restrict__ bias, int act,
                      unsigned short* __restrict__ outbf) {
    int gid = blockIdx.x * 256 + threadIdx.x;
    int b = gid / Np, n = gid % Np;
    float v = 0.0f;
    if (n < realN) {
        v = bias ? bias[n] : 0.0f;
        for (int s = 0; s < nslots; s++) v += part[(size_t)(s * 32 + b) * Np + n];
        if (act) v = tanhf(v);
    }
    outbf[(size_t)b * Np + n] = f2bf(v);
}

__global__ void qbk_k(const unsigned short* __restrict__ q, int Kp, int realK,
                      const float* __restrict__ bk, float* __restrict__ out) {
    int b = blockIdx.x, tid = threadIdx.x;
    float s = 0.f;
    for (int d = tid; d < realK; d += 256) s += bf2f(q[(size_t)b * Kp + d]) * bk[d];
    for (int o = 32; o; o >>= 1) s += __shfl_xor(s, o);
    __shared__ float r[4];
    if ((tid & 63) == 0) r[tid >> 6] = s;
    __syncthreads();
    if (tid == 0) out[b] = r[0] + r[1] + r[2] + r[3];
}

__global__ void scores_k(const unsigned short* __restrict__ hs, const unsigned short* __restrict__ qk,
                         const float* __restrict__ qbk, float* __restrict__ out,
                         int Kp, float scale) {
    int gid = blockIdx.x * 4 + (threadIdx.x >> 6);
    int lane = threadIdx.x & 63;
    int b = gid >> 9, t = gid & 511;
    const unsigned short* hrow = hs + ((size_t)PT(t) * BB + b) * Kp;   // time-permuted ring
    const unsigned short* qrow = qk + (size_t)b * Kp;
    float acc = 0.f;
    for (int kb = lane * 4; kb < Kp; kb += 256) {
        uint2 hv = *reinterpret_cast<const uint2*>(hrow + kb);
        uint2 qv = *reinterpret_cast<const uint2*>(qrow + kb);
        acc += __uint_as_float(hv.x << 16) * __uint_as_float(qv.x << 16);
        acc += __uint_as_float(hv.x & 0xFFFF0000u) * __uint_as_float(qv.x & 0xFFFF0000u);
        acc += __uint_as_float(hv.y << 16) * __uint_as_float(qv.y << 16);
        acc += __uint_as_float(hv.y & 0xFFFF0000u) * __uint_as_float(qv.y & 0xFFFF0000u);
    }
    for (int o = 32; o; o >>= 1) acc += __shfl_xor(acc, o);
    if (lane == 0) out[b * TT + t] = (acc + qbk[b]) * scale;
}

__global__ void softmax_k(const float* __restrict__ in, float* __restrict__ out) {
    int b = blockIdx.x, tid = threadIdx.x;
    float v0 = in[b * TT + tid], v1 = in[b * TT + 256 + tid];
    float mx = fmaxf(v0, v1);
    for (int o = 32; o; o >>= 1) mx = fmaxf(mx, __shfl_xor(mx, o));
    __shared__ float r[4], r2[4];
    int wid = tid >> 6, lane = tid & 63;
    if (lane == 0) r[wid] = mx;
    __syncthreads();
    mx = fmaxf(fmaxf(r[0], r[1]), fmaxf(r[2], r[3]));
    float e0 = expf(v0 - mx), e1 = expf(v1 - mx);
    float s = e0 + e1;
    for (int o = 32; o; o >>= 1) s += __shfl_xor(s, o);
    if (lane == 0) r2[wid] = s;
    __syncthreads();
    s = r2[0] + r2[1] + r2[2] + r2[3];
    float invs = 1.0f / s;
    out[b * TT + tid] = e0 * invs;
    out[b * TT + 256 + tid] = e1 * invs;
}

__global__ void attnsum_k(const unsigned short* __restrict__ hs, const float* __restrict__ aw,
                          unsigned short* __restrict__ out, int Kp) {
    int gid = blockIdx.x * 256 + threadIdx.x;
    int b = gid / Kp, e = gid % Kp;
    float acc = 0.f;
    for (int t = 0; t < TT; t++)
        acc += aw[b * TT + t] * bf2f(hs[((size_t)PT(t) * BB + b) * Kp + e]);   // permuted
    out[(size_t)b * Kp + e] = f2bf(acc);
}

__global__ void cls_k(const unsigned short* __restrict__ h2f, const float* __restrict__ wcls,
                      const float* __restrict__ bcls, float* __restrict__ out) {
    int b = blockIdx.x;
    int wid = threadIdx.x >> 6, lane = threadIdx.x & 63;
    for (int o = wid; o < OO; o += 4) {
        float s = 0.f;
        for (int e = lane; e < EE; e += 64)
            s += bf2f(h2f[(size_t)b * EE + e]) * wcls[o * EE + e];
        for (int off = 32; off; off >>= 1) s += __shfl_xor(s, off);
        if (lane == 0) out[b * OO + o] = s + bcls[o];
    }
}

__global__ void fail_k(float* out) {
    int i = blockIdx.x * 256 + threadIdx.x;
    if (i < BB * OO) out[i] = 1e9f;
}

// =====================================================================
extern "C" void kernel_launch(void* const* d_in, const int* in_sizes, int n_in,
                              void* d_out, int out_size, void* d_ws, size_t ws_size,
                              hipStream_t stream) {
    const float* x        = (const float*)d_in[0];
    const float* in_g     = (const float*)d_in[1];
    const float* in_b     = (const float*)d_in[2];
    const float* w_ih1    = (const float*)d_in[3];
    const float* w_hh1    = (const float*)d_in[4];
    const float* b_ih1    = (const float*)d_in[5];
    const float* b_hh1    = (const float*)d_in[6];
    const float* ln1_g    = (const float*)d_in[7];
    const float* ln1_b    = (const float*)d_in[8];
    const float* w_ih2    = (const float*)d_in[9];
    const float* w_hh2    = (const float*)d_in[10];
    const float* b_ih2    = (const float*)d_in[11];
    const float* b_hh2    = (const float*)d_in[12];
    const float* m1_wqkv  = (const float*)d_in[13];
    const float* m1_bqkv  = (const float*)d_in[14];
    const float* m1_wo    = (const float*)d_in[15];
    const float* m1_bo    = (const float*)d_in[16];
    const float* m2_wqkv  = (const float*)d_in[17];
    const float* m2_bqkv  = (const float*)d_in[18];
    const float* m2_wo    = (const float*)d_in[19];
    const float* m2_bo    = (const float*)d_in[20];
    const float* w_cls    = (const float*)d_in[21];
    const float* b_cls    = (const float*)d_in[22];
    float* out = (float*)d_out;

    const size_t TB = (size_t)TT * BB;
    size_t cur = 0;
    auto alloc = [&](size_t bytes) { cur = (cur + 255) & ~(size_t)255; size_t o = cur; cur += bytes; return o; };
    char* ws = (char*)d_ws;
    #define US(off) ((unsigned short*)(ws + (off)))
    #define FP(off) ((float*)(ws + (off)))

    size_t o_xnhi   = alloc(TB * EE * 2);
    size_t o_xnlo   = alloc(TB * EE * 2);
    size_t o_wih1hi = alloc((size_t)HP * EE * 2);
    size_t o_wih1lo = alloc((size_t)HP * EE * 2);
    size_t o_whh1hi = alloc((size_t)HP * HP * 2);
    size_t o_whh1lo = alloc((size_t)HP * HP * 2);
    size_t o_wih2   = alloc((size_t)EE * HP * 2);
    size_t o_whh2   = alloc((size_t)EE * EE * 2);
    size_t o_h1s    = alloc(TB * HP * 2);   // h1 ring (hi) = snapshot
    size_t o_h2s    = alloc(TB * EE * 2);   // h2 ring (hi) = snapshot
    size_t o_h1nlo  = alloc((size_t)BB * HP * 2);
    size_t o_h2lo   = alloc((size_t)BB * EE * 2);
    size_t o_part1  = alloc((size_t)8 * BB * HP * 4);   // persist_k uses slots 0..6; tail uses 8
    size_t o_part2  = alloc((size_t)8 * BB * EE * 4);
    size_t o_b1c    = alloc((size_t)HP * 4);
    size_t o_b2c    = alloc((size_t)EE * 4);
    size_t o_gpad   = alloc((size_t)HP * 4);
    size_t o_bepad  = alloc((size_t)HP * 4);
    size_t o_sync   = alloc(64 * 128 + 256);
    size_t o_xw1hi  = alloc(TB * HP * 2);   // also overlay region for MHA weights (post-loop)
    size_t o_xw1lo  = alloc(TB * HP * 2);
    size_t o_q1     = alloc((size_t)BB * HP * 2);
    size_t o_qk1    = alloc((size_t)BB * HP * 2);
    size_t o_u1     = alloc((size_t)BB * HP * 2);
    size_t o_vc1    = alloc((size_t)BB * HP * 2);
    size_t o_ctx1   = alloc((size_t)BB * HP * 2);
    size_t o_qbk1   = alloc(BB * 4);
    size_t o_sc1    = alloc((size_t)BB * TT * 4);
    size_t o_aw1    = alloc((size_t)BB * TT * 4);
    size_t o_q2     = alloc((size_t)BB * EE * 2);
    size_t o_qk2    = alloc((size_t)BB * EE * 2);
    size_t o_u2     = alloc((size_t)BB * EE * 2);
    size_t o_vc2    = alloc((size_t)BB * EE * 2);
    size_t o_ctx2   = alloc((size_t)BB * EE * 2);
    size_t o_qbk2   = alloc(BB * 4);
    size_t o_sc2    = alloc((size_t)BB * TT * 4);
    size_t o_aw2    = alloc((size_t)BB * TT * 4);
    size_t o_h1f    = alloc((size_t)BB * HP * 2);
    size_t o_h2f    = alloc((size_t)BB * EE * 2);

    // overlay: MHA weights into xw1 region (dead after the recurrence loop)
    size_t ov = o_xw1hi;
    auto oalloc = [&](size_t bytes) { ov = (ov + 255) & ~(size_t)255; size_t o = ov; ov += bytes; return o; };
    size_t v_wq1  = oalloc((size_t)HP * HP * 2);
    size_t v_wk1T = oalloc((size_t)HP * HP * 2);
    size_t v_wv1  = oalloc((size_t)HP * HP * 2);
    size_t v_wo1  = oalloc((size_t)HP * HP * 2);
    size_t v_wq2  = oalloc((size_t)EE * EE * 2);
    size_t v_wk2T = oalloc((size_t)EE * EE * 2);
    size_t v_wv2  = oalloc((size_t)EE * EE * 2);
    size_t v_wo2  = oalloc((size_t)EE * EE * 2);

    if (ws_size < cur) {
        fail_k<<<3, 256, 0, stream>>>(out);
        return;
    }

    // ---------- prep ----------
    ln_x_k<<<BB * TT, 256, 0, stream>>>(x, in_g, in_b, US(o_xnhi), US(o_xnlo));
    castsplit_k<<<(HP * EE + 255) / 256, 256, 0, stream>>>(w_ih1, HH, EE, US(o_wih1hi), US(o_wih1lo), HP, EE);
    castsplit_k<<<(HP * HP + 255) / 256, 256, 0, stream>>>(w_hh1, HH, HH, US(o_whh1hi), US(o_whh1lo), HP, HP);
    castpad_k<<<(EE * HP + 255) / 256, 256, 0, stream>>>(w_ih2, EE, HH, US(o_wih2), EE, HP);
    castpad_k<<<(EE * EE + 255) / 256, 256, 0, stream>>>(w_hh2, EE, EE, US(o_whh2), EE, EE);
    biascomb_k<<<(HP + 255) / 256, 256, 0, stream>>>(b_ih1, b_hh1, FP(o_b1c), HH, HP);
    biascomb_k<<<(EE + 255) / 256, 256, 0, stream>>>(b_ih2, b_hh2, FP(o_b2c), EE, EE);
    padcopy_k<<<(HP + 255) / 256, 256, 0, stream>>>(ln1_g, FP(o_gpad), HH, HP);
    padcopy_k<<<(HP + 255) / 256, 256, 0, stream>>>(ln1_b, FP(o_bepad), HH, HP);
    hipMemsetAsync(ws + o_sync, 0, 64 * 128 + 256, stream);

    // xw1 = xn @ wih1^T for all t (split precision, bf16 hi/lo out)
    gemmbig_k<<<dim3((int)(TB / 32), HP / 64), 256, 0, stream>>>(US(o_xnhi), US(o_xnlo),
                                                                 US(o_wih1hi), US(o_wih1lo),
                                                                 US(o_xw1hi), US(o_xw1lo), EE, HP, EE / 32);

    // ---------- persistent recurrence ----------
    PP pp;
    pp.xw1hi = US(o_xw1hi); pp.xw1lo = US(o_xw1lo);
    pp.whh1hi = US(o_whh1hi); pp.whh1lo = US(o_whh1lo);
    pp.wih2 = US(o_wih2); pp.whh2 = US(o_whh2);
    pp.b1c = FP(o_b1c); pp.b2c = FP(o_b2c);
    pp.gpad = FP(o_gpad); pp.bepad = FP(o_bepad);
    pp.h1hist = US(o_h1s); pp.h2hist = US(o_h2s);
    pp.h1nlo = US(o_h1nlo); pp.h2lo = US(o_h2lo);
    pp.part1 = FP(o_part1); pp.part2 = FP(o_part2);
    pp.grp = (unsigned int*)(ws + o_sync);
    pp.epoch = (unsigned int*)(ws + o_sync + 64 * 128);
    persist_k<<<NBLK, NTHR, 0, stream>>>(pp);

    // ---------- cast MHA weights into overlay (xw1 dead now; stream-ordered) ----------
    castpad_k<<<(HP * HP + 255) / 256, 256, 0, stream>>>(m1_wqkv, HH, HH, US(v_wq1), HP, HP);
    castpad_k<<<(HP * HP + 255) / 256, 256, 0, stream>>>(m1_wqkv + (size_t)2 * HH * HH, HH, HH, US(v_wv1), HP, HP);
    castpad_k<<<(HP * HP + 255) / 256, 256, 0, stream>>>(m1_wo, HH, HH, US(v_wo1), HP, HP);
    transcast_k<<<dim3(HP / 32, HP / 32), 256, 0, stream>>>(m1_wqkv + (size_t)HH * HH, HH, HH, US(v_wk1T), HP, HP);
    castpad_k<<<(EE * EE + 255) / 256, 256, 0, stream>>>(m2_wqkv, EE, EE, US(v_wq2), EE, EE);
    castpad_k<<<(EE * EE + 255) / 256, 256, 0, stream>>>(m2_wqkv + (size_t)2 * EE * EE, EE, EE, US(v_wv2), EE, EE);
    castpad_k<<<(EE * EE + 255) / 256, 256, 0, stream>>>(m2_wo, EE, EE, US(v_wo2), EE, EE);
    transcast_k<<<dim3(EE / 32, EE / 32), 256, 0, stream>>>(m2_wqkv + (size_t)EE * EE, EE, EE, US(v_wk2T), EE, EE);

    const int PTLAST = (511 * 331) & 511;   // = 181
    const unsigned short* h1last = US(o_h1s) + (size_t)PTLAST * BB * HP;
    const unsigned short* h2last = US(o_h2s) + (size_t)PTLAST * BB * EE;
    const float sc_scale1 = 1.0f / sqrtf((float)HH);
    const float sc_scale2 = 1.0f / sqrtf((float)EE);

    // ---------- MHA1 (only last-row context needed) ----------
    gemm32_k<<<dim3(HP / 64, 7), 256, 0, stream>>>(h1last, US(v_wq1), FP(o_part1), HP, HP, 14, 0);
    epi_k<<<BB * HP / 256, 256, 0, stream>>>(FP(o_part1), 7, HP, HH, m1_bqkv, 0, US(o_q1));
    gemm32_k<<<dim3(HP / 64, 7), 256, 0, stream>>>(US(o_q1), US(v_wk1T), FP(o_part1), HP, HP, 14, 0);
    epi_k<<<BB * HP / 256, 256, 0, stream>>>(FP(o_part1), 7, HP, HH, nullptr, 0, US(o_qk1));
    qbk_k<<<BB, 256, 0, stream>>>(US(o_q1), HP, HH, m1_bqkv + HH, FP(o_qbk1));
    scores_k<<<BB * TT / 4, 256, 0, stream>>>(US(o_h1s), US(o_qk1), FP(o_qbk1), FP(o_sc1), HP, sc_scale1);
    softmax_k<<<BB, 256, 0, stream>>>(FP(o_sc1), FP(o_aw1));
    attnsum_k<<<BB * HP / 256, 256, 0, stream>>>(US(o_h1s), FP(o_aw1), US(o_u1), HP);
    gemm32_k<<<dim3(HP / 64, 7), 256, 0, stream>>>(US(o_u1), US(v_wv1), FP(o_part1), HP, HP, 14, 0);
    epi_k<<<BB * HP / 256, 256, 0, stream>>>(FP(o_part1), 7, HP, HH, m1_bqkv + 2 * HH, 0, US(o_vc1));
    gemm32_k<<<dim3(HP / 64, 7), 256, 0, stream>>>(US(o_vc1), US(v_wo1), FP(o_part1), HP, HP, 14, 0);
    epi_k<<<BB * HP / 256, 256, 0, stream>>>(FP(o_part1), 7, HP, HH, m1_bo, 0, US(o_ctx1));

    // ---------- MHA2 ----------
    gemm32_k<<<dim3(EE / 64, 3), 256, 0, stream>>>(h2last, US(v_wq2), FP(o_part2), EE, EE, 8, 0);
    epi_k<<<BB * EE / 256, 256, 0, stream>>>(FP(o_part2), 3, EE, EE, m2_bqkv, 0, US(o_q2));
    gemm32_k<<<dim3(EE / 64, 3), 256, 0, stream>>>(US(o_q2), US(v_wk2T), FP(o_part2), EE, EE, 8, 0);
    epi_k<<<BB * EE / 256, 256, 0, stream>>>(FP(o_part2), 3, EE, EE, nullptr, 0, US(o_qk2));
    qbk_k<<<BB, 256, 0, stream>>>(US(o_q2), EE, EE, m2_bqkv + EE, FP(o_qbk2));
    scores_k<<<BB * TT / 4, 256, 0, stream>>>(US(o_h2s), US(o_qk2), FP(o_qbk2), FP(o_sc2), EE, sc_scale2);
    softmax_k<<<BB, 256, 0, stream>>>(FP(o_sc2), FP(o_aw2));
    attnsum_k<<<BB * EE / 256, 256, 0, stream>>>(US(o_h2s), FP(o_aw2), US(o_u2), EE);
    gemm32_k<<<dim3(EE / 64, 3), 256, 0, stream>>>(US(o_u2), US(v_wv2), FP(o_part2), EE, EE, 8, 0);
    epi_k<<<BB * EE / 256, 256, 0, stream>>>(FP(o_part2), 3, EE, EE, m2_bqkv + 2 * EE, 0, US(o_vc2));
    gemm32_k<<<dim3(EE / 64, 3), 256, 0, stream>>>(US(o_vc2), US(v_wo2), FP(o_part2), EE, EE, 8, 0);
    epi_k<<<BB * EE / 256, 256, 0, stream>>>(FP(o_part2), 3, EE, EE, m2_bo, 0, US(o_ctx2));

    // ---------- final cells (K = 7*14*32 = 3136 exactly; slots 1..7 + xn slot 0) ----------
    const unsigned short* xnlast = US(o_xnhi) + (size_t)(TT - 1) * BB * EE;
    gemm32_k<<<dim3(HP / 64, 1), 256, 0, stream>>>(xnlast, US(o_wih1hi), FP(o_part1), EE, HP, EE / 32, 0);
    gemm32_k<<<dim3(HP / 64, 7), 256, 0, stream>>>(US(o_ctx1), US(o_whh1hi), FP(o_part1), HP, HP, 14, 1);
    epi_k<<<BB * HP / 256, 256, 0, stream>>>(FP(o_part1), 8, HP, HH, FP(o_b1c), 1, US(o_h1f));
    gemm32_k<<<dim3(EE / 64, 7), 256, 0, stream>>>(US(o_h1f), US(o_wih2), FP(o_part2), HP, EE, 14, 0);
    gemm32_k<<<dim3(EE / 64, 1), 256, 0, stream>>>(US(o_ctx2), US(o_whh2), FP(o_part2), EE, EE, EE / 32, 7);
    epi_k<<<BB * EE / 256, 256, 0, stream>>>(FP(o_part2), 8, EE, EE, FP(o_b2c), 1, US(o_h2f));
    cls_k<<<BB, 256, 0, stream>>>(US(o_h2f), w_cls, b_cls, out);
}

// Round 7
// 17817.529 us; speedup vs baseline: 11.5551x; 1.6072x over previous
//
#include <hip/hip_runtime.h>
#include <cstdint>
#include <cmath>

// ---------------- constants ----------------
#define BB 32
#define TT 512
#define EE 768
#define HH 3132
#define HP 3136   // H padded to mult of 64
#define OO 19

#define NBLK 451
#define NTHR 256
#define WP 456    // Wlds row pitch (elems, mult of 8)
#define AP 232    // Alds row pitch

// phase-A task map: blk 0..342 = T1 (nt=blk/7, ks=blk%7; 64x448 Whh1 tile in LDS)
//                   blk 343..426 = T2 (wih2 64x448 tile in LDS)
//                   blk 427..450 = T3 (whh2 64x384 tile in LDS, kh=idx%2)
// phase-B: blk 0..31 = U1 (h1 finish), blk 32..63 = U2 (h2 finish)

// time-permutation for state rings (kills cross-step address adjacency)
#define PT(t) (((t) * 331) & 511)

typedef __attribute__((ext_vector_type(8))) short s8v;
typedef __attribute__((ext_vector_type(4))) float f4v;
typedef __attribute__((ext_vector_type(8))) unsigned short u16x8;

__device__ __forceinline__ unsigned short f2bf(float f) {
    uint32_t u = __float_as_uint(f);
    uint32_t r = u + 0x7FFFu + ((u >> 16) & 1u);
    return (unsigned short)(r >> 16);
}
__device__ __forceinline__ float bf2f(unsigned short h) {
    return __uint_as_float(((uint32_t)h) << 16);
}

#define MFMA(a, b, c) __builtin_amdgcn_mfma_f32_16x16x32_bf16((a), (b), (c), 0, 0, 0)

// ---- sc1 primitives: LLC-coherent, no cache invalidation ----
__device__ __forceinline__ f4v ld4_sc(const void* p) {
    f4v v;
    asm volatile("global_load_dwordx4 %0, %1, off sc0 sc1" : "=v"(v) : "v"(p) : "memory");
    return v;   // valid only after WAITV()
}
#define WAITV() do { asm volatile("s_waitcnt vmcnt(0)" ::: "memory"); \
                     __builtin_amdgcn_sched_barrier(0); } while (0)
__device__ __forceinline__ void st_sc(float* p, float v) {
    __hip_atomic_store(p, v, __ATOMIC_RELAXED, __HIP_MEMORY_SCOPE_AGENT);
}
__device__ __forceinline__ void st16_sc(void* p, u16x8 v) {
    asm volatile("global_store_dwordx4 %0, %1, off sc0 sc1" :: "v"(p), "v"(v) : "memory");
}
__device__ __forceinline__ void st8_sc(void* p, uint2 v) {
    asm volatile("global_store_dwordx2 %0, %1, off sc0 sc1" :: "v"(p), "v"(v) : "memory");
}

// ---------------- persistent-kernel params ----------------
struct PP {
    const unsigned short *xw1hi, *xw1lo;          // precomputed Wih1@xn (normal reads)
    const unsigned short *whh1hi, *whh1lo, *wih2, *whh2;
    const float *b1c, *b2c, *gpad, *bepad;
    unsigned short *h1hist, *h2hist;              // full-T rings (hi): sc1-written, NORMAL-read
    unsigned short *h1nlo, *h2lo;                 // lo single buffers: sc1 both ways
    float *part1, *part2;                         // sc1 both ways
    unsigned int *grp;                            // 64 groups, 128B stride
    unsigned int *epoch;
};

// ---------------- relaxed hierarchical grid barrier (uneven groups) ----------------
__device__ __forceinline__ void gbar(const PP& p, unsigned int k) {
    __syncthreads();
    asm volatile("s_waitcnt vmcnt(0)" ::: "memory");   // all stores (incl. sc1) ACKed at LLC
    if (threadIdx.x == 0)
        __hip_atomic_fetch_add(&p.grp[(blockIdx.x & 63) * 32], 1u,
                               __ATOMIC_RELAXED, __HIP_MEMORY_SCOPE_AGENT);
    if (blockIdx.x == 0) {
        if (threadIdx.x < 64) {
            // NBLK = 451 = 7*64 + 3 -> groups 0..2 have 8 members, rest 7
            unsigned int mem = 7u + (threadIdx.x < (NBLK & 63) ? 1u : 0u);
            unsigned int tgt = mem * k;
            long g = 0;
            while (__hip_atomic_load(&p.grp[threadIdx.x * 32], __ATOMIC_RELAXED,
                                     __HIP_MEMORY_SCOPE_AGENT) < tgt) {
                __builtin_amdgcn_s_sleep(2);
                if (++g > (1L << 16)) break;
            }
        }
        __syncthreads();
        if (threadIdx.x == 0)
            __hip_atomic_store(p.epoch, k, __ATOMIC_RELAXED, __HIP_MEMORY_SCOPE_AGENT);
    } else {
        if (threadIdx.x == 0) {
            long g = 0;
            while (__hip_atomic_load(p.epoch, __ATOMIC_RELAXED,
                                     __HIP_MEMORY_SCOPE_AGENT) < k) {
                __builtin_amdgcn_s_sleep(2);
                if (++g > (1L << 16)) break;
            }
        }
    }
    __syncthreads();
    asm volatile("" ::: "memory");
}

__global__ __launch_bounds__(NTHR, 2) void persist_k(PP p) {
    __shared__ unsigned short Wlds[64][WP];   // persistent weight tile (hi)
    __shared__ unsigned short Alds[32][AP];   // staged h1lo half-slice
    __shared__ float redS[4], redQ[4];
    const int blk = blockIdx.x, tid = threadIdx.x;
    const int wid = tid >> 6, lane = tid & 63;
    const int r = lane & 15, kg = lane >> 4;
    unsigned int bar = 0;

    const int t1nt = blk / 7,          t1ks = blk % 7;           // blk < 343
    const int t2i  = blk - 343,        t2nt = t2i / 7, t2ks = t2i % 7;
    const int t3i  = blk - 427,        t3nt = t3i / 2, t3kh = t3i % 2;

    // ---------- one-time weight preload into LDS ----------
    if (blk < 343) {
        const unsigned short* src = p.whh1hi + (size_t)(t1nt * 64) * HP + t1ks * 448;
        #pragma unroll
        for (int i = 0; i < 14; ++i) {
            int idx = tid + i * 256;              // 64*448/8 = 3584 16B-groups
            int row = idx / 56, c8 = idx % 56;
            *(uint4*)&Wlds[row][c8 * 8] = *(const uint4*)(src + (size_t)row * HP + c8 * 8);
        }
    } else if (blk < 427) {
        const unsigned short* src = p.wih2 + (size_t)(t2nt * 64) * HP + t2ks * 448;
        #pragma unroll
        for (int i = 0; i < 14; ++i) {
            int idx = tid + i * 256;
            int row = idx / 56, c8 = idx % 56;
            *(uint4*)&Wlds[row][c8 * 8] = *(const uint4*)(src + (size_t)row * HP + c8 * 8);
        }
    } else {
        const unsigned short* src = p.whh2 + (size_t)(t3nt * 64) * EE + t3kh * 384;
        #pragma unroll
        for (int i = 0; i < 12; ++i) {
            int idx = tid + i * 256;              // 64*384/8 = 3072
            int row = idx / 48, c8 = idx % 48;
            *(uint4*)&Wlds[row][c8 * 8] = *(const uint4*)(src + (size_t)row * EE + c8 * 8);
        }
    }
    __syncthreads();

    for (int t = 0; t <= TT; ++t) {
        // ===================== PHASE A =====================
        if (blk < 343) {
            // T1: part1[ks] += Whh1 @ h1[t-1] : hi(LDS)*Ahi(ring) + hi*Alo(LDS-staged sc1) + lo(global)*Ahi
            if (t >= 1 && t <= TT - 1) {
                f4v a0 = {0.f,0.f,0.f,0.f}, a1 = {0.f,0.f,0.f,0.f};
                const unsigned short* Wl = p.whh1lo + (size_t)(t1nt * 64 + wid * 16 + r) * HP + t1ks * 448 + kg * 8;
                const unsigned short* ringb = p.h1hist + (size_t)PT(t - 1) * BB * HP + t1ks * 448 + kg * 8;
                for (int hx = 0; hx < 2; ++hx) {
                    __syncthreads();
                    {   // co-op stage Alds <- h1nlo[0:32][ks*448 + hx*224 .. +224]
                        f4v lv[4];
                        #pragma unroll
                        for (int i = 0; i < 4; ++i) {
                            int idx = tid + i * 256;
                            int row = (idx < 896) ? idx / 28 : 0;
                            int c8  = (idx < 896) ? idx % 28 : 0;
                            lv[i] = ld4_sc(p.h1nlo + (size_t)row * HP + t1ks * 448 + hx * 224 + c8 * 8);
                        }
                        WAITV();
                        #pragma unroll
                        for (int i = 0; i < 4; ++i) {
                            int idx = tid + i * 256;
                            if (idx < 896) {
                                int row = idx / 28, c8 = idx % 28;
                                *(f4v*)&Alds[row][c8 * 8] = lv[i];
                            }
                        }
                    }
                    __syncthreads();
                    const unsigned short* Ah0 = ringb + (size_t)r * HP + hx * 224;
                    const unsigned short* Ah1 = ringb + (size_t)(r + 16) * HP + hx * 224;
                    const unsigned short* Wlh = Wl + hx * 224;
                    #pragma unroll
                    for (int kb = 0; kb < 7; ++kb) {
                        s8v bh  = *(const s8v*)&Wlds[wid * 16 + r][hx * 224 + kb * 32 + kg * 8];
                        s8v bl  = *(const s8v*)(Wlh + kb * 32);
                        s8v ah0 = *(const s8v*)(Ah0 + kb * 32);
                        s8v ah1 = *(const s8v*)(Ah1 + kb * 32);
                        s8v al0 = *(const s8v*)&Alds[r][kb * 32 + kg * 8];
                        s8v al1 = *(const s8v*)&Alds[r + 16][kb * 32 + kg * 8];
                        a0 = MFMA(ah0, bh, a0); a1 = MFMA(ah1, bh, a1);
                        a0 = MFMA(al0, bh, a0); a1 = MFMA(al1, bh, a1);
                        a0 = MFMA(ah0, bl, a0); a1 = MFMA(ah1, bl, a1);
                    }
                }
                int ncol = t1nt * 64 + wid * 16 + r;
                float* pp1 = p.part1 + (size_t)t1ks * BB * HP + ncol;
                #pragma unroll
                for (int q = 0; q < 4; ++q) {
                    st_sc(pp1 + (size_t)(kg * 4 + q) * HP,      a0[q]);
                    st_sc(pp1 + (size_t)(kg * 4 + q + 16) * HP, a1[q]);
                }
            }
        } else if (blk < 427) {
            // T2: part2[ks] = Wih2(LDS) @ h1hi[t-1](ring direct)
            if (t >= 1) {
                const unsigned short* ringb = p.h1hist + (size_t)PT(t - 1) * BB * HP + t2ks * 448 + kg * 8;
                const unsigned short* Ah0 = ringb + (size_t)r * HP;
                const unsigned short* Ah1 = ringb + (size_t)(r + 16) * HP;
                f4v a0 = {0.f,0.f,0.f,0.f}, a1 = {0.f,0.f,0.f,0.f};
                #pragma unroll
                for (int kb = 0; kb < 14; ++kb) {
                    s8v bh  = *(const s8v*)&Wlds[wid * 16 + r][kb * 32 + kg * 8];
                    s8v ah0 = *(const s8v*)(Ah0 + kb * 32);
                    s8v ah1 = *(const s8v*)(Ah1 + kb * 32);
                    a0 = MFMA(ah0, bh, a0); a1 = MFMA(ah1, bh, a1);
                }
                int ncol = t2nt * 64 + wid * 16 + r;
                float* pp2 = p.part2 + (size_t)t2ks * BB * EE + ncol;
                #pragma unroll
                for (int q = 0; q < 4; ++q) {
                    st_sc(pp2 + (size_t)(kg * 4 + q) * EE,      a0[q]);
                    st_sc(pp2 + (size_t)(kg * 4 + q + 16) * EE, a1[q]);
                }
            }
        } else {
            // T3: part2[7+kh] = Whh2(LDS, K-half) @ h2[t-2] (hi ring normal + lo sc1)
            if (t >= 2) {
                const unsigned short* Hh = p.h2hist + (size_t)PT(t - 2) * BB * EE + t3kh * 384 + kg * 8;
                const unsigned short* Hl = p.h2lo + t3kh * 384 + kg * 8;
                f4v a0 = {0.f,0.f,0.f,0.f}, a1 = {0.f,0.f,0.f,0.f};
                #pragma unroll
                for (int c = 0; c < 2; ++c) {
                    f4v v0l[6], v1l[6];
                    #pragma unroll
                    for (int u = 0; u < 6; ++u) {
                        int kb = c * 6 + u;
                        v0l[u] = ld4_sc(Hl + (size_t)r * EE + kb * 32);
                        v1l[u] = ld4_sc(Hl + (size_t)(r + 16) * EE + kb * 32);
                    }
                    WAITV();
                    #pragma unroll
                    for (int u = 0; u < 6; ++u) {
                        int kb = c * 6 + u;
                        s8v bh  = *(const s8v*)&Wlds[wid * 16 + r][kb * 32 + kg * 8];
                        s8v ah0 = *(const s8v*)(Hh + (size_t)r * EE + kb * 32);
                        s8v ah1 = *(const s8v*)(Hh + (size_t)(r + 16) * EE + kb * 32);
                        a0 = MFMA(ah0, bh, a0);
                        a0 = MFMA(__builtin_bit_cast(s8v, v0l[u]), bh, a0);
                        a1 = MFMA(ah1, bh, a1);
                        a1 = MFMA(__builtin_bit_cast(s8v, v1l[u]), bh, a1);
                    }
                }
                int ncol = t3nt * 64 + wid * 16 + r;
                float* pp2 = p.part2 + (size_t)(7 + t3kh) * BB * EE + ncol;
                #pragma unroll
                for (int q = 0; q < 4; ++q) {
                    st_sc(pp2 + (size_t)(kg * 4 + q) * EE,      a0[q]);
                    st_sc(pp2 + (size_t)(kg * 4 + q + 16) * EE, a1[q]);
                }
            }
        }
        gbar(p, ++bar);

        // ===================== PHASE B =====================
        if (blk < 32) {
            // U1: h1[t] = LN(tanh(sum part1 + xw1[t] + b)); write ring hi (sc1) + lo buf (sc1)
            if (t <= TT - 1) {
                const int b = blk;
                const int nb = tid * 16;
                const bool act = (tid < 196);
                float acc[16];
                float s = 0.f, s2 = 0.f;
                if (act) {
                    #pragma unroll
                    for (int k4 = 0; k4 < 4; ++k4) {
                        f4v bb = *(const f4v*)(p.b1c + nb + k4 * 4);
                        #pragma unroll
                        for (int e = 0; e < 4; ++e) acc[k4 * 4 + e] = bb[e];
                    }
                    const u16x8* xh = (const u16x8*)(p.xw1hi + ((size_t)t * BB + b) * HP + nb);
                    const u16x8* xl = (const u16x8*)(p.xw1lo + ((size_t)t * BB + b) * HP + nb);
                    u16x8 h0v = xh[0], h1v = xh[1], l0v = xl[0], l1v = xl[1];
                    #pragma unroll
                    for (int j = 0; j < 8; ++j) acc[j]     += bf2f(h0v[j]) + bf2f(l0v[j]);
                    #pragma unroll
                    for (int j = 0; j < 8; ++j) acc[8 + j] += bf2f(h1v[j]) + bf2f(l1v[j]);
                    if (t > 0) {
                        {   // slots 0..3
                            f4v tmp[16];
                            #pragma unroll
                            for (int sl = 0; sl < 4; ++sl) {
                                const float* base = p.part1 + ((size_t)sl * BB + b) * HP + nb;
                                #pragma unroll
                                for (int k4 = 0; k4 < 4; ++k4) tmp[sl * 4 + k4] = ld4_sc(base + k4 * 4);
                            }
                            WAITV();
                            #pragma unroll
                            for (int sl = 0; sl < 4; ++sl)
                                #pragma unroll
                                for (int k4 = 0; k4 < 4; ++k4)
                                    #pragma unroll
                                    for (int e = 0; e < 4; ++e) acc[k4 * 4 + e] += tmp[sl * 4 + k4][e];
                        }
                        {   // slots 4..6
                            f4v tmp[12];
                            #pragma unroll
                            for (int sl = 0; sl < 3; ++sl) {
                                const float* base = p.part1 + ((size_t)(sl + 4) * BB + b) * HP + nb;
                                #pragma unroll
                                for (int k4 = 0; k4 < 4; ++k4) tmp[sl * 4 + k4] = ld4_sc(base + k4 * 4);
                            }
                            WAITV();
                            #pragma unroll
                            for (int sl = 0; sl < 3; ++sl)
                                #pragma unroll
                                for (int k4 = 0; k4 < 4; ++k4)
                                    #pragma unroll
                                    for (int e = 0; e < 4; ++e) acc[k4 * 4 + e] += tmp[sl * 4 + k4][e];
                        }
                    }
                    #pragma unroll
                    for (int j = 0; j < 16; ++j) {
                        if (nb + j < HH) {
                            float v = tanhf(acc[j]);
                            acc[j] = v; s += v; s2 += v * v;
                        } else acc[j] = 0.f;
                    }
                }
                for (int o = 32; o; o >>= 1) { s += __shfl_xor(s, o); s2 += __shfl_xor(s2, o); }
                if (lane == 0) { redS[wid] = s; redQ[wid] = s2; }
                __syncthreads();
                float S  = redS[0] + redS[1] + redS[2] + redS[3];
                float S2 = redQ[0] + redQ[1] + redQ[2] + redQ[3];
                float mm = S / (float)HH;
                float inv = rsqrtf(S2 / (float)HH - mm * mm + 1e-5f);
                __syncthreads();
                if (act) {
                    u16x8 ho0, ho1, lo0, lo1;
                    #pragma unroll
                    for (int k4 = 0; k4 < 4; ++k4) {
                        f4v gv = *(const f4v*)(p.gpad + nb + k4 * 4);
                        f4v bv = *(const f4v*)(p.bepad + nb + k4 * 4);
                        #pragma unroll
                        for (int e = 0; e < 4; ++e) {
                            int j = k4 * 4 + e, n = nb + j;
                            float o = (n < HH) ? (acc[j] - mm) * inv * gv[e] + bv[e] : 0.f;
                            unsigned short hb = f2bf(o);
                            unsigned short lb = f2bf(o - bf2f(hb));
                            if (j < 8) { ho0[j] = hb; lo0[j] = lb; }
                            else       { ho1[j - 8] = hb; lo1[j - 8] = lb; }
                        }
                    }
                    unsigned short* dh = p.h1hist + ((size_t)PT(t) * BB + b) * HP + nb;
                    unsigned short* dl = p.h1nlo + (size_t)b * HP + nb;
                    st16_sc(dh, ho0); st16_sc(dh + 8, ho1);
                    st16_sc(dl, lo0); st16_sc(dl + 8, lo1);
                }
            }
        } else if (blk < 64) {
            // U2: h2[t-1] = tanh(sum of 9 part2 slots + b); write ring hi (sc1) + lo buf (sc1)
            if (t >= 1) {
                const int b = blk - 32;
                if (tid < 192) {
                    const int nb = tid * 4;
                    f4v a4 = *(const f4v*)(p.b2c + nb);
                    f4v tp[9];
                    #pragma unroll
                    for (int sl = 0; sl < 9; ++sl)
                        tp[sl] = ld4_sc(p.part2 + ((size_t)sl * BB + b) * EE + nb);
                    WAITV();
                    #pragma unroll
                    for (int sl = 0; sl < 9; ++sl) {
                        float w = (t == 1 && sl >= 7) ? 0.f : 1.f;   // h2[-1] = 0
                        #pragma unroll
                        for (int e = 0; e < 4; ++e) a4[e] += w * tp[sl][e];
                    }
                    unsigned short hb4[4], lb4[4];
                    #pragma unroll
                    for (int e = 0; e < 4; ++e) {
                        float v = tanhf(a4[e]);
                        hb4[e] = f2bf(v); lb4[e] = f2bf(v - bf2f(hb4[e]));
                    }
                    uint2 hp_, lp_;
                    hp_.x = (unsigned)hb4[0] | ((unsigned)hb4[1] << 16);
                    hp_.y = (unsigned)hb4[2] | ((unsigned)hb4[3] << 16);
                    lp_.x = (unsigned)lb4[0] | ((unsigned)lb4[1] << 16);
                    lp_.y = (unsigned)lb4[2] | ((unsigned)lb4[3] << 16);
                    st8_sc(p.h2hist + ((size_t)PT(t - 1) * BB + b) * EE + nb, hp_);
                    st8_sc(p.h2lo + (size_t)b * EE + nb, lp_);
                }
            }
        }
        gbar(p, ++bar);
    }
}

// ---------------- prep kernels ----------------
__global__ void ln_x_k(const float* __restrict__ x, const float* __restrict__ g,
                       const float* __restrict__ be, unsigned short* __restrict__ xnhi,
                       unsigned short* __restrict__ xnlo) {
    int bt = blockIdx.x;
    int b = bt >> 9, t = bt & 511;
    const float* row = x + ((size_t)b * TT + t) * EE;
    int tid = threadIdx.x;
    float v0 = row[tid], v1 = row[tid + 256], v2 = row[tid + 512];
    float s = v0 + v1 + v2, s2 = v0 * v0 + v1 * v1 + v2 * v2;
    for (int o = 32; o; o >>= 1) { s += __shfl_xor(s, o); s2 += __shfl_xor(s2, o); }
    __shared__ float r1[4], r2[4];
    int wid = tid >> 6, lane = tid & 63;
    if (lane == 0) { r1[wid] = s; r2[wid] = s2; }
    __syncthreads();
    s = r1[0] + r1[1] + r1[2] + r1[3];
    s2 = r2[0] + r2[1] + r2[2] + r2[3];
    float m = s / (float)EE, var = s2 / (float)EE - m * m;
    float inv = rsqrtf(var + 1e-5f);
    size_t ro = ((size_t)t * BB + b) * EE;
    float vals[3] = {v0, v1, v2};
#pragma unroll
    for (int i = 0; i < 3; i++) {
        int e = tid + i * 256;
        float o = (vals[i] - m) * inv * g[e] + be[e];
        unsigned short hb = f2bf(o);
        xnhi[ro + e] = hb;
        xnlo[ro + e] = f2bf(o - bf2f(hb));
    }
}

__global__ void castpad_k(const float* __restrict__ in, int N, int K,
                          unsigned short* __restrict__ out, int Np, int Kp) {
    size_t gid = (size_t)blockIdx.x * 256 + threadIdx.x;
    if (gid >= (size_t)Np * Kp) return;
    int n = (int)(gid / Kp), k = (int)(gid % Kp);
    out[gid] = (n < N && k < K) ? f2bf(in[(size_t)n * K + k]) : (unsigned short)0;
}

__global__ void castsplit_k(const float* __restrict__ in, int N, int K,
                            unsigned short* __restrict__ hi, unsigned short* __restrict__ lo,
                            int Np, int Kp) {
    size_t gid = (size_t)blockIdx.x * 256 + threadIdx.x;
    if (gid >= (size_t)Np * Kp) return;
    int n = (int)(gid / Kp), k = (int)(gid % Kp);
    float v = (n < N && k < K) ? in[(size_t)n * K + k] : 0.0f;
    unsigned short hb = f2bf(v);
    hi[gid] = hb;
    lo[gid] = f2bf(v - bf2f(hb));
}

__global__ void transcast_k(const float* __restrict__ in, int R, int C,
                            unsigned short* __restrict__ out, int Rp, int Cp) {
    __shared__ float tile[32][33];
    int c0 = blockIdx.x * 32, r0 = blockIdx.y * 32;
    int tx = threadIdx.x & 31, ty = threadIdx.x >> 5;
    for (int i = 0; i < 4; i++) {
        int r = r0 + ty + i * 8, c = c0 + tx;
        tile[ty + i * 8][tx] = (r < R && c < C) ? in[(size_t)r * C + c] : 0.0f;
    }
    __syncthreads();
    for (int i = 0; i < 4; i++) {
        int c = c0 + ty + i * 8, r = r0 + tx;
        if (c < Cp && r < Rp) out[(size_t)c * Rp + r] = f2bf(tile[tx][ty + i * 8]);
    }
}

__global__ void biascomb_k(const float* a, const float* b, float* o, int realN, int Np) {
    int gid = blockIdx.x * 256 + threadIdx.x;
    if (gid >= Np) return;
    o[gid] = (gid < realN) ? a[gid] + b[gid] : 0.0f;
}

__global__ void padcopy_k(const float* in, float* out, int realN, int Np) {
    int gid = blockIdx.x * 256 + threadIdx.x;
    if (gid >= Np) return;
    out[gid] = (gid < realN) ? in[gid] : 0.0f;
}

// big split GEMM: xw1 = xn @ wih1^T, out bf16 hi/lo.  grid (TB/32, HP/64)
__global__ __launch_bounds__(256) void gemmbig_k(const unsigned short* __restrict__ Ahi,
                                                 const unsigned short* __restrict__ Alo,
                                                 const unsigned short* __restrict__ Whi,
                                                 const unsigned short* __restrict__ Wlo,
                                                 unsigned short* __restrict__ outhi,
                                                 unsigned short* __restrict__ outlo,
                                                 int Kld, int Np, int ksteps) {
    int m0 = blockIdx.x * 32;
    int n0 = blockIdx.y * 64;
    int wid = threadIdx.x >> 6, lane = threadIdx.x & 63;
    int r = lane & 15, kg = lane >> 4;
    size_t woff = (size_t)(n0 + wid * 16 + r) * Kld + kg * 8;
    const unsigned short* Whr = Whi + woff;
    const unsigned short* Wlr = Wlo + woff;
    size_t aoff = (size_t)(m0 + r) * Kld + kg * 8;
    const unsigned short* Ah0 = Ahi + aoff;
    const unsigned short* Ah1 = Ah0 + (size_t)16 * Kld;
    const unsigned short* Al0 = Alo + aoff;
    const unsigned short* Al1 = Al0 + (size_t)16 * Kld;
    f4v acc0 = {0.f, 0.f, 0.f, 0.f}, acc1 = {0.f, 0.f, 0.f, 0.f};
#pragma unroll 4
    for (int s = 0; s < ksteps; s++) {
        s8v bh  = *(const s8v*)(Whr + s * 32);
        s8v bl  = *(const s8v*)(Wlr + s * 32);
        s8v a0h = *(const s8v*)(Ah0 + s * 32);
        s8v a1h = *(const s8v*)(Ah1 + s * 32);
        s8v a0l = *(const s8v*)(Al0 + s * 32);
        s8v a1l = *(const s8v*)(Al1 + s * 32);
        acc0 = MFMA(a0h, bh, acc0); acc1 = MFMA(a1h, bh, acc1);
        acc0 = MFMA(a0l, bh, acc0); acc1 = MFMA(a1l, bh, acc1);
        acc0 = MFMA(a0h, bl, acc0); acc1 = MFMA(a1h, bl, acc1);
    }
    int ncol = n0 + wid * 16 + r;
#pragma unroll
    for (int q = 0; q < 4; q++) {
        int m = kg * 4 + q;
        float v0 = acc0[q], v1 = acc1[q];
        unsigned short h0 = f2bf(v0), h1 = f2bf(v1);
        outhi[(size_t)(m0 + m) * Np + ncol]      = h0;
        outlo[(size_t)(m0 + m) * Np + ncol]      = f2bf(v0 - bf2f(h0));
        outhi[(size_t)(m0 + m + 16) * Np + ncol] = h1;
        outlo[(size_t)(m0 + m + 16) * Np + ncol] = f2bf(v1 - bf2f(h1));
    }
}

// ---------------- tail kernels ----------------
__global__ __launch_bounds__(256) void gemm32_k(const unsigned short* __restrict__ A,
                                                const unsigned short* __restrict__ W,
                                                float* __restrict__ part,
                                                int Kld, int Np, int ksteps, int slot_base) {
    int n0 = blockIdx.x * 64;
    int kb = blockIdx.y;
    int k0 = kb * ksteps * 32;
    int wid = threadIdx.x >> 6, lane = threadIdx.x & 63;
    int r = lane & 15, kg = lane >> 4;
    const unsigned short* Wrow = W + (size_t)(n0 + wid * 16 + r) * Kld + k0 + kg * 8;
    const unsigned short* Ar0 = A + (size_t)r * Kld + k0 + kg * 8;
    const unsigned short* Ar1 = Ar0 + (size_t)16 * Kld;
    f4v acc0 = {0.f, 0.f, 0.f, 0.f}, acc1 = {0.f, 0.f, 0.f, 0.f};
#pragma unroll
    for (int s = 0; s < ksteps; s++) {
        s8v bf = *(const s8v*)(Wrow + s * 32);
        s8v a0 = *(const s8v*)(Ar0 + s * 32);
        s8v a1 = *(const s8v*)(Ar1 + s * 32);
        acc0 = MFMA(a0, bf, acc0);
        acc1 = MFMA(a1, bf, acc1);
    }
    int ncol = n0 + wid * 16 + r;
    float* p = part + (size_t)(slot_base + kb) * 32 * Np + ncol;
#pragma unroll
    for (int q = 0; q < 4; q++) {
        int m = kg * 4 + q;
        p[(size_t)m * Np]        = acc0[q];
        p[(size_t)(m + 16) * Np] = acc1[q];
    }
}

__global__ void epi_k(const float* __restrict__ part, int nslots, int Np, int realN,
                      const float* __restrict__ bias, int act,
                      unsigned short* __restrict__ outbf) {
    int gid = blockIdx.x * 256 + threadIdx.x;
    int b = gid / Np, n = gid % Np;
    float v = 0.0f;
    if (n < realN) {
        v = bias ? bias[n] : 0.0f;
        for (int s = 0; s < nslots; s++) v += part[(size_t)(s * 32 + b) * Np + n];
        if (act) v = tanhf(v);
    }
    outbf[(size_t)b * Np + n] = f2bf(v);
}

__global__ void qbk_k(const unsigned short* __restrict__ q, int Kp, int realK,
                      const float* __restrict__ bk, float* __restrict__ out) {
    int b = blockIdx.x, tid = threadIdx.x;
    float s = 0.f;
    for (int d = tid; d < realK; d += 256) s += bf2f(q[(size_t)b * Kp + d]) * bk[d];
    for (int o = 32; o; o >>= 1) s += __shfl_xor(s, o);
    __shared__ float r[4];
    if ((tid & 63) == 0) r[tid >> 6] = s;
    __syncthreads();
    if (tid == 0) out[b] = r[0] + r[1] + r[2] + r[3];
}

__global__ void scores_k(const unsigned short* __restrict__ hs, const unsigned short* __restrict__ qk,
                         const float* __restrict__ qbk, float* __restrict__ out,
                         int Kp, float scale) {
    int gid = blockIdx.x * 4 + (threadIdx.x >> 6);
    int lane = threadIdx.x & 63;
    int b = gid >> 9, t = gid & 511;
    const unsigned short* hrow = hs + ((size_t)PT(t) * BB + b) * Kp;   // time-permuted ring
    const unsigned short* qrow = qk + (size_t)b * Kp;
    float acc = 0.f;
    for (int kb = lane * 4; kb < Kp; kb += 256) {
        uint2 hv = *reinterpret_cast<const uint2*>(hrow + kb);
        uint2 qv = *reinterpret_cast<const uint2*>(qrow + kb);
        acc += __uint_as_float(hv.x << 16) * __uint_as_float(qv.x << 16);
        acc += __uint_as_float(hv.x & 0xFFFF0000u) * __uint_as_float(qv.x & 0xFFFF0000u);
        acc += __uint_as_float(hv.y << 16) * __uint_as_float(qv.y << 16);
        acc += __uint_as_float(hv.y & 0xFFFF0000u) * __uint_as_float(qv.y & 0xFFFF0000u);
    }
    for (int o = 32; o; o >>= 1) acc += __shfl_xor(acc, o);
    if (lane == 0) out[b * TT + t] = (acc + qbk[b]) * scale;
}

__global__ void softmax_k(const float* __restrict__ in, float* __restrict__ out) {
    int b = blockIdx.x, tid = threadIdx.x;
    float v0 = in[b * TT + tid], v1 = in[b * TT + 256 + tid];
    float mx = fmaxf(v0, v1);
    for (int o = 32; o; o >>= 1) mx = fmaxf(mx, __shfl_xor(mx, o));
    __shared__ float r[4], r2[4];
    int wid = tid >> 6, lane = tid & 63;
    if (lane == 0) r[wid] = mx;
    __syncthreads();
    mx = fmaxf(fmaxf(r[0], r[1]), fmaxf(r[2], r[3]));
    float e0 = expf(v0 - mx), e1 = expf(v1 - mx);
    float s = e0 + e1;
    for (int o = 32; o; o >>= 1) s += __shfl_xor(s, o);
    if (lane == 0) r2[wid] = s;
    __syncthreads();
    s = r2[0] + r2[1] + r2[2] + r2[3];
    float invs = 1.0f / s;
    out[b * TT + tid] = e0 * invs;
    out[b * TT + 256 + tid] = e1 * invs;
}

__global__ void attnsum_k(const unsigned short* __restrict__ hs, const float* __restrict__ aw,
                          unsigned short* __restrict__ out, int Kp) {
    int gid = blockIdx.x * 256 + threadIdx.x;
    int b = gid / Kp, e = gid % Kp;
    float acc = 0.f;
    for (int t = 0; t < TT; t++)
        acc += aw[b * TT + t] * bf2f(hs[((size_t)PT(t) * BB + b) * Kp + e]);   // permuted
    out[(size_t)b * Kp + e] = f2bf(acc);
}

__global__ void cls_k(const unsigned short* __restrict__ h2f, const float* __restrict__ wcls,
                      const float* __restrict__ bcls, float* __restrict__ out) {
    int b = blockIdx.x;
    int wid = threadIdx.x >> 6, lane = threadIdx.x & 63;
    for (int o = wid; o < OO; o += 4) {
        float s = 0.f;
        for (int e = lane; e < EE; e += 64)
            s += bf2f(h2f[(size_t)b * EE + e]) * wcls[o * EE + e];
        for (int off = 32; off; off >>= 1) s += __shfl_xor(s, off);
        if (lane == 0) out[b * OO + o] = s + bcls[o];
    }
}

__global__ void fail_k(float* out) {
    int i = blockIdx.x * 256 + threadIdx.x;
    if (i < BB * OO) out[i] = 1e9f;
}

// =====================================================================
extern "C" void kernel_launch(void* const* d_in, const int* in_sizes, int n_in,
                              void* d_out, int out_size, void* d_ws, size_t ws_size,
                              hipStream_t stream) {
    const float* x        = (const float*)d_in[0];
    const float* in_g     = (const float*)d_in[1];
    const float* in_b     = (const float*)d_in[2];
    const float* w_ih1    = (const float*)d_in[3];
    const float* w_hh1    = (const float*)d_in[4];
    const float* b_ih1    = (const float*)d_in[5];
    const float* b_hh1    = (const float*)d_in[6];
    const float* ln1_g    = (const float*)d_in[7];
    const float* ln1_b    = (const float*)d_in[8];
    const float* w_ih2    = (const float*)d_in[9];
    const float* w_hh2    = (const float*)d_in[10];
    const float* b_ih2    = (const float*)d_in[11];
    const float* b_hh2    = (const float*)d_in[12];
    const float* m1_wqkv  = (const float*)d_in[13];
    const float* m1_bqkv  = (const float*)d_in[14];
    const float* m1_wo    = (const float*)d_in[15];
    const float* m1_bo    = (const float*)d_in[16];
    const float* m2_wqkv  = (const float*)d_in[17];
    const float* m2_bqkv  = (const float*)d_in[18];
    const float* m2_wo    = (const float*)d_in[19];
    const float* m2_bo    = (const float*)d_in[20];
    const float* w_cls    = (const float*)d_in[21];
    const float* b_cls    = (const float*)d_in[22];
    float* out = (float*)d_out;

    const size_t TB = (size_t)TT * BB;
    size_t cur = 0;
    auto alloc = [&](size_t bytes) { cur = (cur + 255) & ~(size_t)255; size_t o = cur; cur += bytes; return o; };
    char* ws = (char*)d_ws;
    #define US(off) ((unsigned short*)(ws + (off)))
    #define FP(off) ((float*)(ws + (off)))

    size_t o_xnhi   = alloc(TB * EE * 2);
    size_t o_xnlo   = alloc(TB * EE * 2);
    size_t o_wih1hi = alloc((size_t)HP * EE * 2);
    size_t o_wih1lo = alloc((size_t)HP * EE * 2);
    size_t o_whh1hi = alloc((size_t)HP * HP * 2);
    size_t o_whh1lo = alloc((size_t)HP * HP * 2);
    size_t o_wih2   = alloc((size_t)EE * HP * 2);
    size_t o_whh2   = alloc((size_t)EE * EE * 2);
    size_t o_h1s    = alloc(TB * HP * 2);   // h1 ring (hi) = snapshot
    size_t o_h2s    = alloc(TB * EE * 2);   // h2 ring (hi) = snapshot
    size_t o_h1nlo  = alloc((size_t)BB * HP * 2);
    size_t o_h2lo   = alloc((size_t)BB * EE * 2);
    size_t o_part1  = alloc((size_t)8 * BB * HP * 4);   // persist uses 0..6; tail uses 8
    size_t o_part2  = alloc((size_t)9 * BB * EE * 4);   // persist uses 0..8; tail uses 8
    size_t o_b1c    = alloc((size_t)HP * 4);
    size_t o_b2c    = alloc((size_t)EE * 4);
    size_t o_gpad   = alloc((size_t)HP * 4);
    size_t o_bepad  = alloc((size_t)HP * 4);
    size_t o_sync   = alloc(64 * 128 + 256);
    size_t o_xw1hi  = alloc(TB * HP * 2);   // also overlay region for MHA weights (post-loop)
    size_t o_xw1lo  = alloc(TB * HP * 2);
    size_t o_q1     = alloc((size_t)BB * HP * 2);
    size_t o_qk1    = alloc((size_t)BB * HP * 2);
    size_t o_u1     = alloc((size_t)BB * HP * 2);
    size_t o_vc1    = alloc((size_t)BB * HP * 2);
    size_t o_ctx1   = alloc((size_t)BB * HP * 2);
    size_t o_qbk1   = alloc(BB * 4);
    size_t o_sc1    = alloc((size_t)BB * TT * 4);
    size_t o_aw1    = alloc((size_t)BB * TT * 4);
    size_t o_q2     = alloc((size_t)BB * EE * 2);
    size_t o_qk2    = alloc((size_t)BB * EE * 2);
    size_t o_u2     = alloc((size_t)BB * EE * 2);
    size_t o_vc2    = alloc((size_t)BB * EE * 2);
    size_t o_ctx2   = alloc((size_t)BB * EE * 2);
    size_t o_qbk2   = alloc(BB * 4);
    size_t o_sc2    = alloc((size_t)BB * TT * 4);
    size_t o_aw2    = alloc((size_t)BB * TT * 4);
    size_t o_h1f    = alloc((size_t)BB * HP * 2);
    size_t o_h2f    = alloc((size_t)BB * EE * 2);

    // overlay: MHA weights into xw1 region (dead after the recurrence loop)
    size_t ov = o_xw1hi;
    auto oalloc = [&](size_t bytes) { ov = (ov + 255) & ~(size_t)255; size_t o = ov; ov += bytes; return o; };
    size_t v_wq1  = oalloc((size_t)HP * HP * 2);
    size_t v_wk1T = oalloc((size_t)HP * HP * 2);
    size_t v_wv1  = oalloc((size_t)HP * HP * 2);
    size_t v_wo1  = oalloc((size_t)HP * HP * 2);
    size_t v_wq2  = oalloc((size_t)EE * EE * 2);
    size_t v_wk2T = oalloc((size_t)EE * EE * 2);
    size_t v_wv2  = oalloc((size_t)EE * EE * 2);
    size_t v_wo2  = oalloc((size_t)EE * EE * 2);

    if (ws_size < cur) {
        fail_k<<<3, 256, 0, stream>>>(out);
        return;
    }

    // ---------- prep ----------
    ln_x_k<<<BB * TT, 256, 0, stream>>>(x, in_g, in_b, US(o_xnhi), US(o_xnlo));
    castsplit_k<<<(HP * EE + 255) / 256, 256, 0, stream>>>(w_ih1, HH, EE, US(o_wih1hi), US(o_wih1lo), HP, EE);
    castsplit_k<<<(HP * HP + 255) / 256, 256, 0, stream>>>(w_hh1, HH, HH, US(o_whh1hi), US(o_whh1lo), HP, HP);
    castpad_k<<<(EE * HP + 255) / 256, 256, 0, stream>>>(w_ih2, EE, HH, US(o_wih2), EE, HP);
    castpad_k<<<(EE * EE + 255) / 256, 256, 0, stream>>>(w_hh2, EE, EE, US(o_whh2), EE, EE);
    biascomb_k<<<(HP + 255) / 256, 256, 0, stream>>>(b_ih1, b_hh1, FP(o_b1c), HH, HP);
    biascomb_k<<<(EE + 255) / 256, 256, 0, stream>>>(b_ih2, b_hh2, FP(o_b2c), EE, EE);
    padcopy_k<<<(HP + 255) / 256, 256, 0, stream>>>(ln1_g, FP(o_gpad), HH, HP);
    padcopy_k<<<(HP + 255) / 256, 256, 0, stream>>>(ln1_b, FP(o_bepad), HH, HP);
    hipMemsetAsync(ws + o_sync, 0, 64 * 128 + 256, stream);

    // xw1 = xn @ wih1^T for all t (split precision, bf16 hi/lo out)
    gemmbig_k<<<dim3((int)(TB / 32), HP / 64), 256, 0, stream>>>(US(o_xnhi), US(o_xnlo),
                                                                 US(o_wih1hi), US(o_wih1lo),
                                                                 US(o_xw1hi), US(o_xw1lo), EE, HP, EE / 32);

    // ---------- persistent recurrence ----------
    PP pp;
    pp.xw1hi = US(o_xw1hi); pp.xw1lo = US(o_xw1lo);
    pp.whh1hi = US(o_whh1hi); pp.whh1lo = US(o_whh1lo);
    pp.wih2 = US(o_wih2); pp.whh2 = US(o_whh2);
    pp.b1c = FP(o_b1c); pp.b2c = FP(o_b2c);
    pp.gpad = FP(o_gpad); pp.bepad = FP(o_bepad);
    pp.h1hist = US(o_h1s); pp.h2hist = US(o_h2s);
    pp.h1nlo = US(o_h1nlo); pp.h2lo = US(o_h2lo);
    pp.part1 = FP(o_part1); pp.part2 = FP(o_part2);
    pp.grp = (unsigned int*)(ws + o_sync);
    pp.epoch = (unsigned int*)(ws + o_sync + 64 * 128);
    persist_k<<<NBLK, NTHR, 0, stream>>>(pp);

    // ---------- cast MHA weights into overlay (xw1 dead now; stream-ordered) ----------
    castpad_k<<<(HP * HP + 255) / 256, 256, 0, stream>>>(m1_wqkv, HH, HH, US(v_wq1), HP, HP);
    castpad_k<<<(HP * HP + 255) / 256, 256, 0, stream>>>(m1_wqkv + (size_t)2 * HH * HH, HH, HH, US(v_wv1), HP, HP);
    castpad_k<<<(HP * HP + 255) / 256, 256, 0, stream>>>(m1_wo, HH, HH, US(v_wo1), HP, HP);
    transcast_k<<<dim3(HP / 32, HP / 32), 256, 0, stream>>>(m1_wqkv + (size_t)HH * HH, HH, HH, US(v_wk1T), HP, HP);
    castpad_k<<<(EE * EE + 255) / 256, 256, 0, stream>>>(m2_wqkv, EE, EE, US(v_wq2), EE, EE);
    castpad_k<<<(EE * EE + 255) / 256, 256, 0, stream>>>(m2_wqkv + (size_t)2 * EE * EE, EE, EE, US(v_wv2), EE, EE);
    castpad_k<<<(EE * EE + 255) / 256, 256, 0, stream>>>(m2_wo, EE, EE, US(v_wo2), EE, EE);
    transcast_k<<<dim3(EE / 32, EE / 32), 256, 0, stream>>>(m2_wqkv + (size_t)EE * EE, EE, EE, US(v_wk2T), EE, EE);

    const int PTLAST = (511 * 331) & 511;   // = 181
    const unsigned short* h1last = US(o_h1s) + (size_t)PTLAST * BB * HP;
    const unsigned short* h2last = US(o_h2s) + (size_t)PTLAST * BB * EE;
    const float sc_scale1 = 1.0f / sqrtf((float)HH);
    const float sc_scale2 = 1.0f / sqrtf((float)EE);

    // ---------- MHA1 (only last-row context needed) ----------
    gemm32_k<<<dim3(HP / 64, 7), 256, 0, stream>>>(h1last, US(v_wq1), FP(o_part1), HP, HP, 14, 0);
    epi_k<<<BB * HP / 256, 256, 0, stream>>>(FP(o_part1), 7, HP, HH, m1_bqkv, 0, US(o_q1));
    gemm32_k<<<dim3(HP / 64, 7), 256, 0, stream>>>(US(o_q1), US(v_wk1T), FP(o_part1), HP, HP, 14, 0);
    epi_k<<<BB * HP / 256, 256, 0, stream>>>(FP(o_part1), 7, HP, HH, nullptr, 0, US(o_qk1));
    qbk_k<<<BB, 256, 0, stream>>>(US(o_q1), HP, HH, m1_bqkv + HH, FP(o_qbk1));
    scores_k<<<BB * TT / 4, 256, 0, stream>>>(US(o_h1s), US(o_qk1), FP(o_qbk1), FP(o_sc1), HP, sc_scale1);
    softmax_k<<<BB, 256, 0, stream>>>(FP(o_sc1), FP(o_aw1));
    attnsum_k<<<BB * HP / 256, 256, 0, stream>>>(US(o_h1s), FP(o_aw1), US(o_u1), HP);
    gemm32_k<<<dim3(HP / 64, 7), 256, 0, stream>>>(US(o_u1), US(v_wv1), FP(o_part1), HP, HP, 14, 0);
    epi_k<<<BB * HP / 256, 256, 0, stream>>>(FP(o_part1), 7, HP, HH, m1_bqkv + 2 * HH, 0, US(o_vc1));
    gemm32_k<<<dim3(HP / 64, 7), 256, 0, stream>>>(US(o_vc1), US(v_wo1), FP(o_part1), HP, HP, 14, 0);
    epi_k<<<BB * HP / 256, 256, 0, stream>>>(FP(o_part1), 7, HP, HH, m1_bo, 0, US(o_ctx1));

    // ---------- MHA2 ----------
    gemm32_k<<<dim3(EE / 64, 3), 256, 0, stream>>>(h2last, US(v_wq2), FP(o_part2), EE, EE, 8, 0);
    epi_k<<<BB * EE / 256, 256, 0, stream>>>(FP(o_part2), 3, EE, EE, m2_bqkv, 0, US(o_q2));
    gemm32_k<<<dim3(EE / 64, 3), 256, 0, stream>>>(US(o_q2), US(v_wk2T), FP(o_part2), EE, EE, 8, 0);
    epi_k<<<BB * EE / 256, 256, 0, stream>>>(FP(o_part2), 3, EE, EE, nullptr, 0, US(o_qk2));
    qbk_k<<<BB, 256, 0, stream>>>(US(o_q2), EE, EE, m2_bqkv + EE, FP(o_qbk2));
    scores_k<<<BB * TT / 4, 256, 0, stream>>>(US(o_h2s), US(o_qk2), FP(o_qbk2), FP(o_sc2), EE, sc_scale2);
    softmax_k<<<BB, 256, 0, stream>>>(FP(o_sc2), FP(o_aw2));
    attnsum_k<<<BB * EE / 256, 256, 0, stream>>>(US(o_h2s), FP(o_aw2), US(o_u2), EE);
    gemm32_k<<<dim3(EE / 64, 3), 256, 0, stream>>>(US(o_u2), US(v_wv2), FP(o_part2), EE, EE, 8, 0);
    epi_k<<<BB * EE / 256, 256, 0, stream>>>(FP(o_part2), 3, EE, EE, m2_bqkv + 2 * EE, 0, US(o_vc2));
    gemm32_k<<<dim3(EE / 64, 3), 256, 0, stream>>>(US(o_vc2), US(v_wo2), FP(o_part2), EE, EE, 8, 0);
    epi_k<<<BB * EE / 256, 256, 0, stream>>>(FP(o_part2), 3, EE, EE, m2_bo, 0, US(o_ctx2));

    // ---------- final cells (K = 7*14*32 = 3136 exactly; slots 1..7 + xn slot 0) ----------
    const unsigned short* xnlast = US(o_xnhi) + (size_t)(TT - 1) * BB * EE;
    gemm32_k<<<dim3(HP / 64, 1), 256, 0, stream>>>(xnlast, US(o_wih1hi), FP(o_part1), EE, HP, EE / 32, 0);
    gemm32_k<<<dim3(HP / 64, 7), 256, 0, stream>>>(US(o_ctx1), US(o_whh1hi), FP(o_part1), HP, HP, 14, 1);
    epi_k<<<BB * HP / 256, 256, 0, stream>>>(FP(o_part1), 8, HP, HH, FP(o_b1c), 1, US(o_h1f));
    gemm32_k<<<dim3(EE / 64, 7), 256, 0, stream>>>(US(o_h1f), US(o_wih2), FP(o_part2), HP, EE, 14, 0);
    gemm32_k<<<dim3(EE / 64, 1), 256, 0, stream>>>(US(o_ctx2), US(o_whh2), FP(o_part2), EE, EE, EE / 32, 7);
    epi_k<<<BB * EE / 256, 256, 0, stream>>>(FP(o_part2), 8, EE, EE, FP(o_b2c), 1, US(o_h2f));
    cls_k<<<BB, 256, 0, stream>>>(US(o_h2f), w_cls, b_cls, out);
}